// Round 1
// baseline (2364.699 us; speedup 1.0000x reference)
//
#include <hip/hip_runtime.h>
#include <hip/hip_bf16.h>

#define D_MODEL 1024
#define N_HEADS 16
#define D_HEAD 64
#define MAX_K_LEN 1024
#define B_SZ 2
#define TQ 1024
#define TK 1024
#define M_ROWS (B_SZ * TQ)   // 2048
#define NKL (N_HEADS * MAX_K_LEN)  // 16384

// ---------------------------------------------------------------------------
// Generic tiled f32 GEMM: C[M,N] = act(A[M,K] @ W[K,N] + bias[N])
// BM=BN=128, BK=16, 256 threads, 8x8 per-thread micro-tile.
// ACT: 0 = identity, 1 = exact GELU.
// ---------------------------------------------------------------------------
__device__ inline void store_out(float* p, float v) { *p = v; }
__device__ inline void store_out(__hip_bfloat16* p, float v) { *p = __float2bfloat16(v); }

template <int ACT, typename OUT_T>
__global__ __launch_bounds__(256) void gemm_tile(
    const float* __restrict__ A, const float* __restrict__ W,
    const float* __restrict__ bias, OUT_T* __restrict__ C,
    int M, int N, int K)
{
    const int tid = threadIdx.x;
    const int n0 = blockIdx.x * 128;
    const int m0 = blockIdx.y * 128;

    __shared__ float As[16][128];   // [k][m]
    __shared__ float Ws[16][128];   // [k][n]

    float acc[8][8];
#pragma unroll
    for (int i = 0; i < 8; ++i)
#pragma unroll
        for (int j = 0; j < 8; ++j) acc[i][j] = 0.f;

    const int tx = tid & 15;        // 0..15 -> n sub-block
    const int ty = tid >> 4;        // 0..15 -> m sub-block
    const int arow = tid >> 1;          // 0..127
    const int akc  = (tid & 1) * 8;     // 0 or 8

    for (int k0 = 0; k0 < K; k0 += 16) {
        // load A tile (128 x 16), transposed into As[k][m]
        {
            const float* ap = A + (size_t)(m0 + arow) * K + k0 + akc;
            float4 a0 = *(const float4*)ap;
            float4 a1 = *(const float4*)(ap + 4);
            As[akc + 0][arow] = a0.x; As[akc + 1][arow] = a0.y;
            As[akc + 2][arow] = a0.z; As[akc + 3][arow] = a0.w;
            As[akc + 4][arow] = a1.x; As[akc + 5][arow] = a1.y;
            As[akc + 6][arow] = a1.z; As[akc + 7][arow] = a1.w;
        }
        // load W tile (16 x 128)
#pragma unroll
        for (int r = 0; r < 8; ++r) {
            int idx = tid + 256 * r;
            int kk = idx >> 7, n = idx & 127;
            Ws[kk][n] = W[(size_t)(k0 + kk) * N + n0 + n];
        }
        __syncthreads();

#pragma unroll
        for (int kk = 0; kk < 16; ++kk) {
            float4 a0 = *(const float4*)&As[kk][ty * 8];
            float4 a1 = *(const float4*)&As[kk][ty * 8 + 4];
            float4 b0 = *(const float4*)&Ws[kk][tx * 8];
            float4 b1 = *(const float4*)&Ws[kk][tx * 8 + 4];
            float a[8] = {a0.x, a0.y, a0.z, a0.w, a1.x, a1.y, a1.z, a1.w};
            float b[8] = {b0.x, b0.y, b0.z, b0.w, b1.x, b1.y, b1.z, b1.w};
#pragma unroll
            for (int i = 0; i < 8; ++i)
#pragma unroll
                for (int j = 0; j < 8; ++j) acc[i][j] += a[i] * b[j];
        }
        __syncthreads();
    }

#pragma unroll
    for (int i = 0; i < 8; ++i) {
        int m = m0 + ty * 8 + i;
#pragma unroll
        for (int j = 0; j < 8; ++j) {
            int n = n0 + tx * 8 + j;
            float c = acc[i][j] + bias[n];
            if (ACT == 1) c = 0.5f * c * (1.f + erff(c * 0.70710678118654752f));
            store_out(&C[(size_t)m * N + n], c);
        }
    }
}

// ---------------------------------------------------------------------------
// Fused gated attention: one block per (q, h, b).
// logits[k] = (1-g) * (Q.K) * scale + g * S[b,q,h,k]  (k <= q, kpm keep)
// softmax over k, then ctx[d] = sum_k p[k] * V[b,k,h,d]
// ---------------------------------------------------------------------------
__device__ inline float wave_max(float v) {
#pragma unroll
    for (int o = 32; o > 0; o >>= 1) v = fmaxf(v, __shfl_xor(v, o));
    return v;
}
__device__ inline float wave_sum(float v) {
#pragma unroll
    for (int o = 32; o > 0; o >>= 1) v += __shfl_xor(v, o);
    return v;
}

__global__ __launch_bounds__(256) void attn_fused(
    const float* __restrict__ Q, const float* __restrict__ Kf,
    const float* __restrict__ Vf, const __hip_bfloat16* __restrict__ S,
    const int* __restrict__ kpm, const float* __restrict__ gate,
    float* __restrict__ ctx)
{
    const int q = blockIdx.x, h = blockIdx.y, b = blockIdx.z;
    const int tid = threadIdx.x;

    __shared__ __align__(16) float qrow[64];
    __shared__ float p_lds[TK];
    __shared__ float red[4];
    __shared__ float psum[4][64];

    const float g = 1.f / (1.f + expf(-gate[h]));
    const float vscale = (1.f - g) * 0.125f;   // (1-g) * dh^-0.5

    if (tid < 64)
        qrow[tid] = Q[((size_t)(b * TQ) + q) * D_MODEL + h * 64 + tid];
    __syncthreads();

    const int kend = q + 1;   // causal

    float lmax = -INFINITY;
    for (int k = tid; k < kend; k += 256) {
        float logit = -INFINITY;
        if (kpm[b * TK + k] > 0) {
            const float4* kr = (const float4*)&Kf[((size_t)(b * TK) + k) * D_MODEL + h * 64];
            const float4* qr = (const float4*)qrow;
            float dot = 0.f;
#pragma unroll
            for (int d4 = 0; d4 < 16; ++d4) {
                float4 kv = kr[d4], qv = qr[d4];
                dot += kv.x * qv.x + kv.y * qv.y + kv.z * qv.z + kv.w * qv.w;
            }
            float s = __bfloat162float(S[((size_t)(b * TQ) + q) * NKL + (size_t)h * MAX_K_LEN + k]);
            logit = vscale * dot + g * s;
        }
        p_lds[k] = logit;
        lmax = fmaxf(lmax, logit);
    }
    lmax = wave_max(lmax);
    if ((tid & 63) == 0) red[tid >> 6] = lmax;
    __syncthreads();
    const float m = fmaxf(fmaxf(red[0], red[1]), fmaxf(red[2], red[3]));
    __syncthreads();   // protect red before reuse

    float lsum = 0.f;
    for (int k = tid; k < kend; k += 256) {
        float p = expf(p_lds[k] - m);
        p_lds[k] = p;
        lsum += p;
    }
    lsum = wave_sum(lsum);
    if ((tid & 63) == 0) red[tid >> 6] = lsum;
    __syncthreads();   // also makes all p_lds writes visible
    const float inv = 1.f / (red[0] + red[1] + red[2] + red[3]);

    // PV: chunk c handles k ≡ c (mod 4); lanes within a chunk cover d=0..63
    const int c = tid >> 6, d = tid & 63;
    float acc = 0.f;
    for (int k = c; k < kend; k += 4)
        acc += p_lds[k] * Vf[((size_t)(b * TK) + k) * D_MODEL + h * 64 + d];
    psum[c][d] = acc;
    __syncthreads();
    if (tid < 64) {
        float r = (psum[0][tid] + psum[1][tid] + psum[2][tid] + psum[3][tid]) * inv;
        ctx[((size_t)(b * TQ) + q) * D_MODEL + h * 64 + tid] = r;
    }
}

// ---------------------------------------------------------------------------
extern "C" void kernel_launch(void* const* d_in, const int* in_sizes, int n_in,
                              void* d_out, int out_size, void* d_ws, size_t ws_size,
                              hipStream_t stream) {
    const float* x_q  = (const float*)d_in[0];
    const float* x_kv = (const float*)d_in[1];
    const int*   kpm  = (const int*)d_in[2];
    const float* Wq   = (const float*)d_in[3];
    const float* bq   = (const float*)d_in[4];
    const float* Wk   = (const float*)d_in[5];
    const float* bk   = (const float*)d_in[6];
    const float* Wv   = (const float*)d_in[7];
    const float* bv   = (const float*)d_in[8];
    const float* Wo   = (const float*)d_in[9];
    const float* bo   = (const float*)d_in[10];
    const float* Ws1  = (const float*)d_in[11];
    const float* bs1  = (const float*)d_in[12];
    const float* Ws2  = (const float*)d_in[13];
    const float* bs2  = (const float*)d_in[14];
    const float* gate = (const float*)d_in[15];

    char* ws = (char*)d_ws;
    const size_t MAT = (size_t)M_ROWS * D_MODEL;           // 2M elements
    float* Qb  = (float*)ws;                               // 8 MB
    float* Kb  = Qb + MAT;                                 // 8 MB
    float* Vb  = Kb + MAT;                                 // 8 MB
    float* hb  = Vb + MAT;                                 // 8 MB
    __hip_bfloat16* Sb = (__hip_bfloat16*)(hb + MAT);      // 64 MB
    float* ctx = (float*)(Sb + (size_t)M_ROWS * NKL);      // 8 MB

    dim3 blk(256);
    dim3 g_small(D_MODEL / 128, M_ROWS / 128);   // (8,16)
    dim3 g_big(NKL / 128, M_ROWS / 128);         // (128,16)

    gemm_tile<0, float><<<g_small, blk, 0, stream>>>(x_q,  Wq,  bq,  Qb, M_ROWS, D_MODEL, D_MODEL);
    gemm_tile<0, float><<<g_small, blk, 0, stream>>>(x_kv, Wk,  bk,  Kb, M_ROWS, D_MODEL, D_MODEL);
    gemm_tile<0, float><<<g_small, blk, 0, stream>>>(x_kv, Wv,  bv,  Vb, M_ROWS, D_MODEL, D_MODEL);
    gemm_tile<1, float><<<g_small, blk, 0, stream>>>(x_q,  Ws1, bs1, hb, M_ROWS, D_MODEL, D_MODEL);
    gemm_tile<0, __hip_bfloat16><<<g_big, blk, 0, stream>>>(hb, Ws2, bs2, Sb, M_ROWS, NKL, D_MODEL);

    attn_fused<<<dim3(TQ, N_HEADS, B_SZ), blk, 0, stream>>>(Qb, Kb, Vb, Sb, kpm, gate, ctx);

    gemm_tile<0, float><<<g_small, blk, 0, stream>>>(ctx, Wo, bo, (float*)d_out, M_ROWS, D_MODEL, D_MODEL);
}

// Round 2
// 569.583 us; speedup vs baseline: 4.1516x; 4.1516x over previous
//
#include <hip/hip_runtime.h>
#include <hip/hip_bf16.h>

#define D_MODEL 1024
#define N_HEADS 16
#define MAX_K_LEN 1024
#define B_SZ 2
#define TQ 1024
#define TK 1024
#define M_ROWS 2048
#define NKL 16384

using bf16x8 = __attribute__((ext_vector_type(8))) short;
using f32x4  = __attribute__((ext_vector_type(4))) float;
using u16x8  = __attribute__((ext_vector_type(8))) unsigned short;

__device__ __forceinline__ unsigned short f2b(float f) {
    unsigned u = __float_as_uint(f);
    u = (u + 0x7FFFu + ((u >> 16) & 1u)) >> 16;
    return (unsigned short)u;
}
__device__ __forceinline__ float b2f(unsigned short u) {
    return __uint_as_float(((unsigned)u) << 16);
}

// async global->LDS, 16B per lane (linear LDS dest: wave base + lane*16)
__device__ __forceinline__ void async_cp16(void* lds, const void* g) {
    __builtin_amdgcn_global_load_lds(
        (__attribute__((address_space(1))) void*)(void*)g,
        (__attribute__((address_space(3))) void*)lds, 16, 0, 0);
}

// ---------------------------------------------------------------------------
// bf16 MFMA GEMM core: C[M,N] = act(A[M,K] @ Wt[N,K]^T + bias)
// 128x128 tile, BK=32, 256 threads (4 waves, 2x2), 4x4 16x16x32 frags/wave.
// ---------------------------------------------------------------------------
__device__ __forceinline__ void gemm_core(
    const unsigned short* __restrict__ A, const unsigned short* __restrict__ Wt,
    const float* __restrict__ bias, void* __restrict__ Cv,
    unsigned short* As, unsigned short* Bs,
    int N, int K, int m0, int n0, int act, int outbf)
{
    const int tid = threadIdx.x;
    const int lane = tid & 63;
    const int wv = tid >> 6, wr = wv >> 1, wc = wv & 1;

    f32x4 acc[4][4];
#pragma unroll
    for (int i = 0; i < 4; ++i)
#pragma unroll
        for (int j = 0; j < 4; ++j) { f32x4 z = {0.f,0.f,0.f,0.f}; acc[i][j] = z; }

    const int srow = tid >> 2, sch = (tid & 3) * 8;
    const unsigned short* gA0 = A  + (size_t)(m0 + srow) * K + sch;
    const unsigned short* gB0 = Wt + (size_t)(n0 + srow) * K + sch;
    const unsigned short* gA1 = gA0 + (size_t)64 * K;
    const unsigned short* gB1 = gB0 + (size_t)64 * K;
    unsigned short* lA = As + tid * 8;
    unsigned short* lB = Bs + tid * 8;

    const int fr = lane & 15, fk = (lane >> 4) * 8;

    for (int k0 = 0; k0 < K; k0 += 32) {
        async_cp16(lA,        gA0 + k0);
        async_cp16(lA + 2048, gA1 + k0);
        async_cp16(lB,        gB0 + k0);
        async_cp16(lB + 2048, gB1 + k0);
        __syncthreads();

        bf16x8 af[4], bfr[4];
#pragma unroll
        for (int i = 0; i < 4; ++i) {
            af[i]  = *(const bf16x8*)(As + (wr*64 + i*16 + fr)*32 + fk);
            bfr[i] = *(const bf16x8*)(Bs + (wc*64 + i*16 + fr)*32 + fk);
        }
#pragma unroll
        for (int mi = 0; mi < 4; ++mi)
#pragma unroll
            for (int ni = 0; ni < 4; ++ni)
                acc[mi][ni] = __builtin_amdgcn_mfma_f32_16x16x32_bf16(
                    af[mi], bfr[ni], acc[mi][ni], 0, 0, 0);
        __syncthreads();
    }

    // epilogue: C/D layout col=lane&15, row=(lane>>4)*4+r
    const int cr = (lane >> 4) * 4, cc = lane & 15;
#pragma unroll
    for (int mi = 0; mi < 4; ++mi) {
#pragma unroll
        for (int ni = 0; ni < 4; ++ni) {
            const int col = n0 + wc*64 + ni*16 + cc;
            const float bv = bias[col];
#pragma unroll
            for (int r = 0; r < 4; ++r) {
                const int row = m0 + wr*64 + mi*16 + cr + r;
                float c = acc[mi][ni][r] + bv;
                if (act) c = 0.5f * c * (1.f + erff(c * 0.70710678118654752f));
                if (outbf) ((unsigned short*)Cv)[(size_t)row * N + col] = f2b(c);
                else       ((float*)Cv)[(size_t)row * N + col] = c;
            }
        }
    }
}

__global__ __launch_bounds__(256) void gemm_bf16(
    const unsigned short* __restrict__ A, const unsigned short* __restrict__ Wt,
    const float* __restrict__ bias, void* __restrict__ C,
    int N, int K, int act, int outbf)
{
    __shared__ __align__(16) unsigned short As[128*32];
    __shared__ __align__(16) unsigned short Bs[128*32];
    gemm_core(A, Wt, bias, C, As, Bs, N, K, blockIdx.y*128, blockIdx.x*128, act, outbf);
}

struct QkvhArgs {
    const unsigned short* A[4];
    const unsigned short* W[4];
    const float* bias[4];
    void* out[4];
};

__global__ __launch_bounds__(256) void gemm_qkvh(QkvhArgs args) {
    __shared__ __align__(16) unsigned short As[128*32];
    __shared__ __align__(16) unsigned short Bs[128*32];
    const int z = blockIdx.z;
    gemm_core(args.A[z], args.W[z], args.bias[z], args.out[z], As, Bs,
              D_MODEL, D_MODEL, blockIdx.y*128, blockIdx.x*128, (z == 3) ? 1 : 0, 1);
}

// ---------------------------------------------------------------------------
// conversions
// ---------------------------------------------------------------------------
__global__ __launch_bounds__(256) void conv_b(const float* __restrict__ in,
                                              unsigned short* __restrict__ out, int n4) {
    const int i = blockIdx.x * 256 + threadIdx.x;
    if (i < n4) {
        const float4 v = ((const float4*)in)[i];
        ushort4 o; o.x = f2b(v.x); o.y = f2b(v.y); o.z = f2b(v.z); o.w = f2b(v.w);
        ((ushort4*)out)[i] = o;
    }
}

// W[K,N] f32 -> Wt[N,K] bf16, 32x32 tiles
__global__ __launch_bounds__(256) void conv_t(const float* __restrict__ W,
                                              unsigned short* __restrict__ Wt,
                                              int K, int N) {
    __shared__ float T[32][33];
    const int n0 = blockIdx.x * 32, k0 = blockIdx.y * 32;
    const int r = threadIdx.x >> 3, c = (threadIdx.x & 7) * 4;
    const float4 v = *(const float4*)&W[(size_t)(k0 + r) * N + n0 + c];
    T[r][c] = v.x; T[r][c+1] = v.y; T[r][c+2] = v.z; T[r][c+3] = v.w;
    __syncthreads();
    ushort4 o;
    o.x = f2b(T[c][r]); o.y = f2b(T[c+1][r]); o.z = f2b(T[c+2][r]); o.w = f2b(T[c+3][r]);
    *(ushort4*)&Wt[(size_t)(n0 + r) * K + k0 + c] = o;
}

// ---------------------------------------------------------------------------
// flash attention: block = (qtile=32 rows, h, b), 256 threads.
// thread (qp=tid>>4, kp=tid&15): logits micro-tile 2q x 4k (k = kp+16j),
// PV micro-tile 2q x 4d (d = kp*4..). Online softmax per q-row (16-lane reduce).
// ---------------------------------------------------------------------------
__global__ __launch_bounds__(256) void attn_flash(
    const unsigned short* __restrict__ Qb, const unsigned short* __restrict__ Kb,
    const unsigned short* __restrict__ Vb, const unsigned short* __restrict__ Sb,
    const int* __restrict__ kpm, const float* __restrict__ gate,
    unsigned short* __restrict__ ctx)
{
    const int qt = blockIdx.x, h = blockIdx.y, b = blockIdx.z;
    const int tid = threadIdx.x;
    const int qp = tid >> 4, kp = tid & 15;

    __shared__ float Qs[32][68];
    __shared__ float Ks[64][68];
    __shared__ float Vs[64][68];
    __shared__ float Ps[32][68];

    const float g = 1.f / (1.f + __expf(-gate[h]));
    const float vsc = (1.f - g) * 0.125f;   // (1-g) * dh^-0.5
    const int q0g = qt * 32;

    {   // stage Q (bf16 -> f32): 32 rows x 64
        const int r = tid >> 3, c = (tid & 7) * 8;
        const u16x8 v = *(const u16x8*)(Qb + ((size_t)(b*TQ) + q0g + r) * D_MODEL + h*64 + c);
#pragma unroll
        for (int j = 0; j < 8; ++j) Qs[r][c + j] = b2f(v[j]);
    }

    float mrun[2] = {-INFINITY, -INFINITY};
    float lrun[2] = {0.f, 0.f};
    float a0[4] = {0,0,0,0}, a1[4] = {0,0,0,0};

    const int kend = q0g + 32;              // causal bound, <= TK
    const int ntiles = (kend + 63) >> 6;

    for (int kt = 0; kt < ntiles; ++kt) {
        __syncthreads();                    // prev PV done; Qs visible (iter 0)
        {   // stage K,V tile 64x64 (bf16 -> f32)
            const int r = tid >> 2, c = (tid & 3) * 16;
            const size_t base = ((size_t)(b*TK) + kt*64 + r) * D_MODEL + h*64 + c;
            const u16x8 k0v = *(const u16x8*)(Kb + base);
            const u16x8 k1v = *(const u16x8*)(Kb + base + 8);
            const u16x8 v0v = *(const u16x8*)(Vb + base);
            const u16x8 v1v = *(const u16x8*)(Vb + base + 8);
#pragma unroll
            for (int j = 0; j < 8; ++j) {
                Ks[r][c + j] = b2f(k0v[j]);  Ks[r][c + 8 + j] = b2f(k1v[j]);
                Vs[r][c + j] = b2f(v0v[j]);  Vs[r][c + 8 + j] = b2f(v1v[j]);
            }
        }
        __syncthreads();

        float dot[2][4] = {{0,0,0,0},{0,0,0,0}};
#pragma unroll
        for (int d4 = 0; d4 < 16; ++d4) {
            const float4 q0v = *(const float4*)&Qs[2*qp][d4*4];
            const float4 q1v = *(const float4*)&Qs[2*qp+1][d4*4];
#pragma unroll
            for (int j = 0; j < 4; ++j) {
                const float4 kv = *(const float4*)&Ks[kp + 16*j][d4*4];
                dot[0][j] += q0v.x*kv.x + q0v.y*kv.y + q0v.z*kv.z + q0v.w*kv.w;
                dot[1][j] += q1v.x*kv.x + q1v.y*kv.y + q1v.z*kv.z + q1v.w*kv.w;
            }
        }

        float s[2][4], tmax[2] = {-INFINITY, -INFINITY};
#pragma unroll
        for (int j = 0; j < 4; ++j) {
            const int kg = kt*64 + kp + 16*j;
            const bool kvalid = (kpm[b*TK + kg] > 0);
#pragma unroll
            for (int qi = 0; qi < 2; ++qi) {
                const int qg = q0g + 2*qp + qi;
                float sv = -INFINITY;
                if (kvalid && kg <= qg) {
                    const float syn = b2f(Sb[((size_t)(b*TQ) + qg) * NKL + h*MAX_K_LEN + kg]);
                    sv = vsc * dot[qi][j] + g * syn;
                }
                s[qi][j] = sv;
                tmax[qi] = fmaxf(tmax[qi], sv);
            }
        }
#pragma unroll
        for (int o = 1; o < 16; o <<= 1) {
            tmax[0] = fmaxf(tmax[0], __shfl_xor(tmax[0], o));
            tmax[1] = fmaxf(tmax[1], __shfl_xor(tmax[1], o));
        }

        float sc[2], tsum[2] = {0.f, 0.f};
#pragma unroll
        for (int qi = 0; qi < 2; ++qi) {
            const float mn = fmaxf(mrun[qi], tmax[qi]);
            sc[qi] = (mrun[qi] == -INFINITY) ? 0.f : __expf(mrun[qi] - mn);
            mrun[qi] = mn;
        }
#pragma unroll
        for (int qi = 0; qi < 2; ++qi)
#pragma unroll
            for (int j = 0; j < 4; ++j) {
                const float p = (s[qi][j] == -INFINITY) ? 0.f : __expf(s[qi][j] - mrun[qi]);
                Ps[2*qp + qi][kp + 16*j] = p;
                tsum[qi] += p;
            }
#pragma unroll
        for (int o = 1; o < 16; o <<= 1) {
            tsum[0] += __shfl_xor(tsum[0], o);
            tsum[1] += __shfl_xor(tsum[1], o);
        }
        lrun[0] = lrun[0]*sc[0] + tsum[0];
        lrun[1] = lrun[1]*sc[1] + tsum[1];
#pragma unroll
        for (int x = 0; x < 4; ++x) { a0[x] *= sc[0]; a1[x] *= sc[1]; }
        __syncthreads();                    // Ps visible

        const int dc = kp * 4;
#pragma unroll 8
        for (int k = 0; k < 64; ++k) {
            const float4 v = *(const float4*)&Vs[k][dc];
            const float p0 = Ps[2*qp][k], p1 = Ps[2*qp+1][k];
            a0[0] += p0*v.x; a0[1] += p0*v.y; a0[2] += p0*v.z; a0[3] += p0*v.w;
            a1[0] += p1*v.x; a1[1] += p1*v.y; a1[2] += p1*v.z; a1[3] += p1*v.w;
        }
    }

    const float inv0 = (lrun[0] > 0.f) ? 1.f/lrun[0] : 0.f;
    const float inv1 = (lrun[1] > 0.f) ? 1.f/lrun[1] : 0.f;
    const size_t obase = ((size_t)(b*TQ) + q0g + 2*qp) * D_MODEL + h*64 + kp*4;
    ushort4 o0, o1;
    o0.x = f2b(a0[0]*inv0); o0.y = f2b(a0[1]*inv0); o0.z = f2b(a0[2]*inv0); o0.w = f2b(a0[3]*inv0);
    o1.x = f2b(a1[0]*inv1); o1.y = f2b(a1[1]*inv1); o1.z = f2b(a1[2]*inv1); o1.w = f2b(a1[3]*inv1);
    *(ushort4*)(ctx + obase) = o0;
    *(ushort4*)(ctx + obase + D_MODEL) = o1;
}

// ---------------------------------------------------------------------------
extern "C" void kernel_launch(void* const* d_in, const int* in_sizes, int n_in,
                              void* d_out, int out_size, void* d_ws, size_t ws_size,
                              hipStream_t stream) {
    const float* x_q  = (const float*)d_in[0];
    const float* x_kv = (const float*)d_in[1];
    const int*   kpm  = (const int*)d_in[2];
    const float* Wq  = (const float*)d_in[3];  const float* bq  = (const float*)d_in[4];
    const float* Wk  = (const float*)d_in[5];  const float* bk  = (const float*)d_in[6];
    const float* Wv  = (const float*)d_in[7];  const float* bv  = (const float*)d_in[8];
    const float* Wo  = (const float*)d_in[9];  const float* bo  = (const float*)d_in[10];
    const float* Ws1 = (const float*)d_in[11]; const float* bs1 = (const float*)d_in[12];
    const float* Ws2 = (const float*)d_in[13]; const float* bs2 = (const float*)d_in[14];
    const float* gate = (const float*)d_in[15];

    char* ws = (char*)d_ws;
    const size_t MB = 1024ull * 1024ull;
    // Sb (64MB) overlays xq_b/xkv_b (dead before Sb is written)
    unsigned short* Sb    = (unsigned short*)ws;
    unsigned short* xq_b  = (unsigned short*)ws;               // 4MB
    unsigned short* xkv_b = (unsigned short*)(ws + 4*MB);      // 4MB
    size_t off = 64*MB;
    unsigned short* Wq_t  = (unsigned short*)(ws + off); off += 2*MB;
    unsigned short* Wk_t  = (unsigned short*)(ws + off); off += 2*MB;
    unsigned short* Wv_t  = (unsigned short*)(ws + off); off += 2*MB;
    unsigned short* Wo_t  = (unsigned short*)(ws + off); off += 2*MB;
    unsigned short* Ws1_t = (unsigned short*)(ws + off); off += 2*MB;
    unsigned short* Ws2_t = (unsigned short*)(ws + off); off += 32*MB;
    unsigned short* Qb    = (unsigned short*)(ws + off); off += 4*MB;
    unsigned short* Kb    = (unsigned short*)(ws + off); off += 4*MB;
    unsigned short* Vb    = (unsigned short*)(ws + off); off += 4*MB;
    unsigned short* hb    = (unsigned short*)(ws + off); off += 4*MB;
    unsigned short* ctxb  = (unsigned short*)(ws + off); off += 4*MB;

    dim3 blk(256);
    const int n4 = M_ROWS * D_MODEL / 4;
    conv_b<<<dim3((n4 + 255) / 256), blk, 0, stream>>>(x_q,  xq_b,  n4);
    conv_b<<<dim3((n4 + 255) / 256), blk, 0, stream>>>(x_kv, xkv_b, n4);
    conv_t<<<dim3(D_MODEL/32, D_MODEL/32), blk, 0, stream>>>(Wq,  Wq_t,  D_MODEL, D_MODEL);
    conv_t<<<dim3(D_MODEL/32, D_MODEL/32), blk, 0, stream>>>(Wk,  Wk_t,  D_MODEL, D_MODEL);
    conv_t<<<dim3(D_MODEL/32, D_MODEL/32), blk, 0, stream>>>(Wv,  Wv_t,  D_MODEL, D_MODEL);
    conv_t<<<dim3(D_MODEL/32, D_MODEL/32), blk, 0, stream>>>(Wo,  Wo_t,  D_MODEL, D_MODEL);
    conv_t<<<dim3(D_MODEL/32, D_MODEL/32), blk, 0, stream>>>(Ws1, Ws1_t, D_MODEL, D_MODEL);
    conv_t<<<dim3(NKL/32,     D_MODEL/32), blk, 0, stream>>>(Ws2, Ws2_t, D_MODEL, NKL);

    QkvhArgs qa;
    qa.A[0] = xq_b;  qa.W[0] = Wq_t;  qa.bias[0] = bq;  qa.out[0] = Qb;
    qa.A[1] = xkv_b; qa.W[1] = Wk_t;  qa.bias[1] = bk;  qa.out[1] = Kb;
    qa.A[2] = xkv_b; qa.W[2] = Wv_t;  qa.bias[2] = bv;  qa.out[2] = Vb;
    qa.A[3] = xq_b;  qa.W[3] = Ws1_t; qa.bias[3] = bs1; qa.out[3] = hb;
    gemm_qkvh<<<dim3(D_MODEL/128, M_ROWS/128, 4), blk, 0, stream>>>(qa);

    gemm_bf16<<<dim3(NKL/128, M_ROWS/128), blk, 0, stream>>>(hb, Ws2_t, bs2, Sb, NKL, D_MODEL, 0, 1);

    attn_flash<<<dim3(TQ/32, N_HEADS, B_SZ), blk, 0, stream>>>(Qb, Kb, Vb, Sb, kpm, gate, ctxb);

    gemm_bf16<<<dim3(D_MODEL/128, M_ROWS/128), blk, 0, stream>>>(ctxb, Wo_t, bo, d_out, D_MODEL, D_MODEL, 0, 0);
}

// Round 3
// 248.216 us; speedup vs baseline: 9.5268x; 2.2947x over previous
//
#include <hip/hip_runtime.h>
#include <hip/hip_bf16.h>

#define D_MODEL 1024
#define N_HEADS 16
#define MAX_K_LEN 1024
#define B_SZ 2
#define TQ 1024
#define TK 1024
#define M_ROWS 2048
#define NKL 16384

using bf16x8 = __attribute__((ext_vector_type(8))) short;
using f32x4  = __attribute__((ext_vector_type(4))) float;
using u16x8  = __attribute__((ext_vector_type(8))) unsigned short;

__device__ __forceinline__ unsigned short f2b(float f) {
    unsigned u = __float_as_uint(f);
    u = (u + 0x7FFFu + ((u >> 16) & 1u)) >> 16;
    return (unsigned short)u;
}
__device__ __forceinline__ float b2f(unsigned short u) {
    return __uint_as_float(((unsigned)u) << 16);
}

// async global->LDS, 16B per lane (linear LDS dest: wave base + lane*16)
__device__ __forceinline__ void async_cp16(void* lds, const void* g) {
    __builtin_amdgcn_global_load_lds(
        (__attribute__((address_space(1))) void*)(void*)g,
        (__attribute__((address_space(3))) void*)lds, 16, 0, 0);
}

// chunk swizzle: 16B-chunk permutation within a 128B row (bijective per row)
__device__ __forceinline__ int xrow(int row) {
    return (row & 7) ^ (((row >> 3) & 3) << 1);
}

// ---------------------------------------------------------------------------
// bf16 MFMA GEMM core: C[M,N] = act(A[M,K] @ Wt[N,K]^T + bias)
// 128x128 tile, BK=32, 256 threads (4 waves, 2x2), 4x4 16x16x32 frags/wave.
// ---------------------------------------------------------------------------
__device__ __forceinline__ void gemm_core(
    const unsigned short* __restrict__ A, const unsigned short* __restrict__ Wt,
    const float* __restrict__ bias, void* __restrict__ Cv,
    unsigned short* As, unsigned short* Bs,
    int N, int K, int m0, int n0, int act, int outbf)
{
    const int tid = threadIdx.x;
    const int lane = tid & 63;
    const int wv = tid >> 6, wr = wv >> 1, wc = wv & 1;

    f32x4 acc[4][4];
#pragma unroll
    for (int i = 0; i < 4; ++i)
#pragma unroll
        for (int j = 0; j < 4; ++j) { f32x4 z = {0.f,0.f,0.f,0.f}; acc[i][j] = z; }

    const int srow = tid >> 2, sch = (tid & 3) * 8;
    const unsigned short* gA0 = A  + (size_t)(m0 + srow) * K + sch;
    const unsigned short* gB0 = Wt + (size_t)(n0 + srow) * K + sch;
    const unsigned short* gA1 = gA0 + (size_t)64 * K;
    const unsigned short* gB1 = gB0 + (size_t)64 * K;
    unsigned short* lA = As + tid * 8;
    unsigned short* lB = Bs + tid * 8;

    const int fr = lane & 15, fk = (lane >> 4) * 8;

    for (int k0 = 0; k0 < K; k0 += 32) {
        async_cp16(lA,        gA0 + k0);
        async_cp16(lA + 2048, gA1 + k0);
        async_cp16(lB,        gB0 + k0);
        async_cp16(lB + 2048, gB1 + k0);
        __syncthreads();

        bf16x8 af[4], bfr[4];
#pragma unroll
        for (int i = 0; i < 4; ++i) {
            af[i]  = *(const bf16x8*)(As + (wr*64 + i*16 + fr)*32 + fk);
            bfr[i] = *(const bf16x8*)(Bs + (wc*64 + i*16 + fr)*32 + fk);
        }
#pragma unroll
        for (int mi = 0; mi < 4; ++mi)
#pragma unroll
            for (int ni = 0; ni < 4; ++ni)
                acc[mi][ni] = __builtin_amdgcn_mfma_f32_16x16x32_bf16(
                    af[mi], bfr[ni], acc[mi][ni], 0, 0, 0);
        __syncthreads();
    }

    const int cr = (lane >> 4) * 4, cc = lane & 15;
#pragma unroll
    for (int mi = 0; mi < 4; ++mi) {
#pragma unroll
        for (int ni = 0; ni < 4; ++ni) {
            const int colx = n0 + wc*64 + ni*16 + cc;
            const float bv = bias[colx];
#pragma unroll
            for (int r = 0; r < 4; ++r) {
                const int row = m0 + wr*64 + mi*16 + cr + r;
                float c = acc[mi][ni][r] + bv;
                if (act) c = 0.5f * c * (1.f + erff(c * 0.70710678118654752f));
                if (outbf) ((unsigned short*)Cv)[(size_t)row * N + colx] = f2b(c);
                else       ((float*)Cv)[(size_t)row * N + colx] = c;
            }
        }
    }
}

__global__ __launch_bounds__(256) void gemm_bf16(
    const unsigned short* __restrict__ A, const unsigned short* __restrict__ Wt,
    const float* __restrict__ bias, void* __restrict__ C,
    int N, int K, int act, int outbf)
{
    __shared__ __align__(16) unsigned short As[128*32];
    __shared__ __align__(16) unsigned short Bs[128*32];
    gemm_core(A, Wt, bias, C, As, Bs, N, K, blockIdx.y*128, blockIdx.x*128, act, outbf);
}

struct QkvhArgs {
    const unsigned short* A[4];
    const unsigned short* W[4];
    const float* bias[4];
    void* out[4];
};

__global__ __launch_bounds__(256) void gemm_qkvh(QkvhArgs args) {
    __shared__ __align__(16) unsigned short As[128*32];
    __shared__ __align__(16) unsigned short Bs[128*32];
    const int z = blockIdx.z;
    gemm_core(args.A[z], args.W[z], args.bias[z], args.out[z], As, Bs,
              D_MODEL, D_MODEL, blockIdx.y*128, blockIdx.x*128, (z == 3) ? 1 : 0, 1);
}

// ---------------------------------------------------------------------------
// conversions
// ---------------------------------------------------------------------------
__global__ __launch_bounds__(256) void conv_b(const float* __restrict__ in,
                                              unsigned short* __restrict__ out, int n4) {
    const int i = blockIdx.x * 256 + threadIdx.x;
    if (i < n4) {
        const float4 v = ((const float4*)in)[i];
        ushort4 o; o.x = f2b(v.x); o.y = f2b(v.y); o.z = f2b(v.z); o.w = f2b(v.w);
        ((ushort4*)out)[i] = o;
    }
}

// W[K,N] f32 -> Wt[N,K] bf16, 32x32 tiles
__global__ __launch_bounds__(256) void conv_t(const float* __restrict__ W,
                                              unsigned short* __restrict__ Wt,
                                              int K, int N) {
    __shared__ float T[32][33];
    const int n0 = blockIdx.x * 32, k0 = blockIdx.y * 32;
    const int r = threadIdx.x >> 3, c = (threadIdx.x & 7) * 4;
    const float4 v = *(const float4*)&W[(size_t)(k0 + r) * N + n0 + c];
    T[r][c] = v.x; T[r][c+1] = v.y; T[r][c+2] = v.z; T[r][c+3] = v.w;
    __syncthreads();
    ushort4 o;
    o.x = f2b(T[c][r]); o.y = f2b(T[c+1][r]); o.z = f2b(T[c+2][r]); o.w = f2b(T[c+3][r]);
    *(ushort4*)&Wt[(size_t)(n0 + r) * K + k0 + c] = o;
}

// ---------------------------------------------------------------------------
// MFMA flash attention: block = (q-tile 64, h, b), 4 waves; wave owns 16 q.
// Per 64-k tile: QK^T (MFMA) + gate/synth/mask + online softmax + PV (MFMA).
// All LDS tiles use the xrow chunk swizzle (<=2-way conflicts).
// ---------------------------------------------------------------------------
__global__ __launch_bounds__(256) void attn_mfma(
    const unsigned short* __restrict__ Qb, const unsigned short* __restrict__ Kb,
    const unsigned short* __restrict__ Vb, const unsigned short* __restrict__ Sb,
    const int* __restrict__ kpm, const float* __restrict__ gate,
    unsigned short* __restrict__ ctx)
{
    const int bx = blockIdx.x;
    const int q1 = bx >> 1;
    const int qt = (bx & 1) ? q1 : (15 - q1);   // heavy/light interleave
    const int h = blockIdx.y, b = blockIdx.z;
    const int tid = threadIdx.x;
    const int lane = tid & 63;
    const int w = tid >> 6;
    const int col = lane & 15, rg = lane >> 4;

    __shared__ __align__(16) unsigned short Qs[64*64];
    __shared__ __align__(16) unsigned short Ks[64*64];
    __shared__ __align__(16) unsigned short Ss[64*64];
    __shared__ __align__(16) unsigned short Vt[64*64];
    __shared__ __align__(16) unsigned short Pl[4*16*64];

    const float g = 1.f / (1.f + __expf(-gate[h]));
    const float vsc = (1.f - g) * 0.125f;       // (1-g) * dh^-0.5
    const int q0g = qt * 64;

    {   // stage Q (swizzled source, linear LDS)
        const unsigned short* gq = Qb + ((size_t)(b*TQ + q0g)) * D_MODEL + h*64;
        const int r = tid >> 3, cp = tid & 7;
        async_cp16(Qs + tid*8,        gq + (size_t)r*D_MODEL + (cp ^ xrow(r))*8);
        async_cp16(Qs + 2048 + tid*8, gq + (size_t)(r+32)*D_MODEL + (cp ^ xrow(r+32))*8);
    }
    __syncthreads();
    bf16x8 af[2];
    {
        const int qrow = w*16 + col;
        af[0] = *(const bf16x8*)(Qs + qrow*64 + ((rg)     ^ xrow(qrow))*8);
        af[1] = *(const bf16x8*)(Qs + qrow*64 + ((4 + rg) ^ xrow(qrow))*8);
    }

    float mrun[4] = {-INFINITY,-INFINITY,-INFINITY,-INFINITY};
    float lrun[4] = {0.f,0.f,0.f,0.f};
    f32x4 octx[4];
#pragma unroll
    for (int n = 0; n < 4; ++n) { f32x4 z = {0.f,0.f,0.f,0.f}; octx[n] = z; }

    unsigned short* Pw = Pl + w*(16*64);

    for (int kt = 0; kt <= qt; ++kt) {
        __syncthreads();                         // prev tile reads complete
        {   // stage K and S tiles
            const int r = tid >> 3, cp = tid & 7;
            const unsigned short* gk = Kb + ((size_t)(b*TK + kt*64)) * D_MODEL + h*64;
            async_cp16(Ks + tid*8,        gk + (size_t)r*D_MODEL + (cp ^ xrow(r))*8);
            async_cp16(Ks + 2048 + tid*8, gk + (size_t)(r+32)*D_MODEL + (cp ^ xrow(r+32))*8);
            const unsigned short* gs = Sb + ((size_t)(b*TQ + q0g)) * NKL + h*MAX_K_LEN + kt*64;
            async_cp16(Ss + tid*8,        gs + (size_t)r*NKL + (cp ^ xrow(r))*8);
            async_cp16(Ss + 2048 + tid*8, gs + (size_t)(r+32)*NKL + (cp ^ xrow(r+32))*8);
        }
        {   // stage V transposed (reg -> swizzled scalar LDS writes)
            const int vk = tid >> 2, vdc = (tid & 3) * 16;
            const unsigned short* gv = Vb + ((size_t)(b*TK + kt*64 + vk)) * D_MODEL + h*64 + vdc;
            const u16x8 v0 = *(const u16x8*)gv;
            const u16x8 v1 = *(const u16x8*)(gv + 8);
            const int kc = vk >> 3, ke = vk & 7;
#pragma unroll
            for (int j = 0; j < 8; ++j) {
                const int d0 = vdc + j, d1 = vdc + 8 + j;
                Vt[d0*64 + (kc ^ xrow(d0))*8 + ke] = v0[j];
                Vt[d1*64 + (kc ^ xrow(d1))*8 + ke] = v1[j];
            }
        }
        int kvalid[4];
#pragma unroll
        for (int n = 0; n < 4; ++n)
            kvalid[n] = kpm[b*TK + kt*64 + n*16 + col];
        __syncthreads();                         // staging visible

        // --- QK^T: 8 MFMA ---
        f32x4 acc[4];
#pragma unroll
        for (int n = 0; n < 4; ++n) { f32x4 z = {0.f,0.f,0.f,0.f}; acc[n] = z; }
#pragma unroll
        for (int ds = 0; ds < 2; ++ds) {
#pragma unroll
            for (int n = 0; n < 4; ++n) {
                const int kr = n*16 + col;
                const bf16x8 bk = *(const bf16x8*)(Ks + kr*64 + ((ds*4 + rg) ^ xrow(kr))*8);
                acc[n] = __builtin_amdgcn_mfma_f32_16x16x32_bf16(af[ds], bk, acc[n], 0, 0, 0);
            }
        }

        // --- gate + synth + mask, online softmax ---
        const bool diag = (kt == qt);
        float tmax[4] = {-INFINITY,-INFINITY,-INFINITY,-INFINITY};
#pragma unroll
        for (int n = 0; n < 4; ++n) {
            const int kl = n*16 + col;
            const int sw = ((kl >> 3) ^ 0) * 0;  // placeholder to keep indices clear
            (void)sw;
#pragma unroll
            for (int r = 0; r < 4; ++r) {
                const int ql = w*16 + rg*4 + r;
                const float syn = b2f(Ss[ql*64 + (((kl>>3) ^ xrow(ql)))*8 + (kl&7)]);
                const bool ok = (kvalid[n] > 0) && (!diag || kl <= ql);
                const float sv = ok ? (vsc*acc[n][r] + g*syn) : -INFINITY;
                acc[n][r] = sv;
                tmax[r] = fmaxf(tmax[r], sv);
            }
        }
#pragma unroll
        for (int o = 1; o < 16; o <<= 1) {
#pragma unroll
            for (int r = 0; r < 4; ++r) tmax[r] = fmaxf(tmax[r], __shfl_xor(tmax[r], o));
        }
        float sc[4];
#pragma unroll
        for (int r = 0; r < 4; ++r) {
            const float mn = fmaxf(mrun[r], tmax[r]);
            sc[r] = (mrun[r] == -INFINITY) ? 0.f : __expf(mrun[r] - mn);
            mrun[r] = mn;
        }
        float tsum[4] = {0.f,0.f,0.f,0.f};
#pragma unroll
        for (int n = 0; n < 4; ++n)
#pragma unroll
            for (int r = 0; r < 4; ++r) {
                const float p = (acc[n][r] == -INFINITY) ? 0.f : __expf(acc[n][r] - mrun[r]);
                acc[n][r] = p;
                tsum[r] += p;
            }
#pragma unroll
        for (int o = 1; o < 16; o <<= 1) {
#pragma unroll
            for (int r = 0; r < 4; ++r) tsum[r] += __shfl_xor(tsum[r], o);
        }
#pragma unroll
        for (int r = 0; r < 4; ++r) lrun[r] = lrun[r]*sc[r] + tsum[r];
#pragma unroll
        for (int n = 0; n < 4; ++n)
#pragma unroll
            for (int r = 0; r < 4; ++r) octx[n][r] *= sc[r];

        // --- P -> per-wave LDS (bf16, swizzled) ---
#pragma unroll
        for (int n = 0; n < 4; ++n) {
            const int kc = n*16 + col;
#pragma unroll
            for (int r = 0; r < 4; ++r) {
                const int q = rg*4 + r;
                Pw[q*64 + (((kc>>3) ^ xrow(q)))*8 + (kc&7)] = f2b(acc[n][r]);
            }
        }

        // --- PV: 8 MFMA ---
#pragma unroll
        for (int ks = 0; ks < 2; ++ks) {
            const bf16x8 pa = *(const bf16x8*)(Pw + col*64 + ((ks*4 + rg) ^ xrow(col))*8);
#pragma unroll
            for (int n = 0; n < 4; ++n) {
                const int d = n*16 + col;
                const bf16x8 vv = *(const bf16x8*)(Vt + d*64 + ((ks*4 + rg) ^ xrow(d))*8);
                octx[n] = __builtin_amdgcn_mfma_f32_16x16x32_bf16(pa, vv, octx[n], 0, 0, 0);
            }
        }
    }

    // epilogue
    float inv[4];
#pragma unroll
    for (int r = 0; r < 4; ++r) inv[r] = (lrun[r] > 0.f) ? 1.f/lrun[r] : 0.f;
#pragma unroll
    for (int n = 0; n < 4; ++n)
#pragma unroll
        for (int r = 0; r < 4; ++r) {
            const size_t row = (size_t)(b*TQ + q0g + w*16 + rg*4 + r);
            ctx[row*D_MODEL + h*64 + n*16 + col] = f2b(octx[n][r]*inv[r]);
        }
}

// ---------------------------------------------------------------------------
extern "C" void kernel_launch(void* const* d_in, const int* in_sizes, int n_in,
                              void* d_out, int out_size, void* d_ws, size_t ws_size,
                              hipStream_t stream) {
    const float* x_q  = (const float*)d_in[0];
    const float* x_kv = (const float*)d_in[1];
    const int*   kpm  = (const int*)d_in[2];
    const float* Wq  = (const float*)d_in[3];  const float* bq  = (const float*)d_in[4];
    const float* Wk  = (const float*)d_in[5];  const float* bk  = (const float*)d_in[6];
    const float* Wv  = (const float*)d_in[7];  const float* bv  = (const float*)d_in[8];
    const float* Wo  = (const float*)d_in[9];  const float* bo  = (const float*)d_in[10];
    const float* Ws1 = (const float*)d_in[11]; const float* bs1 = (const float*)d_in[12];
    const float* Ws2 = (const float*)d_in[13]; const float* bs2 = (const float*)d_in[14];
    const float* gate = (const float*)d_in[15];

    char* ws = (char*)d_ws;
    const size_t MB = 1024ull * 1024ull;
    // Sb (64MB) overlays xq_b/xkv_b (dead before Sb is written)
    unsigned short* Sb    = (unsigned short*)ws;
    unsigned short* xq_b  = (unsigned short*)ws;               // 4MB
    unsigned short* xkv_b = (unsigned short*)(ws + 4*MB);      // 4MB
    size_t off = 64*MB;
    unsigned short* Wq_t  = (unsigned short*)(ws + off); off += 2*MB;
    unsigned short* Wk_t  = (unsigned short*)(ws + off); off += 2*MB;
    unsigned short* Wv_t  = (unsigned short*)(ws + off); off += 2*MB;
    unsigned short* Wo_t  = (unsigned short*)(ws + off); off += 2*MB;
    unsigned short* Ws1_t = (unsigned short*)(ws + off); off += 2*MB;
    unsigned short* Ws2_t = (unsigned short*)(ws + off); off += 32*MB;
    unsigned short* Qb    = (unsigned short*)(ws + off); off += 4*MB;
    unsigned short* Kb    = (unsigned short*)(ws + off); off += 4*MB;
    unsigned short* Vb    = (unsigned short*)(ws + off); off += 4*MB;
    unsigned short* hb    = (unsigned short*)(ws + off); off += 4*MB;
    unsigned short* ctxb  = (unsigned short*)(ws + off); off += 4*MB;

    dim3 blk(256);
    const int n4 = M_ROWS * D_MODEL / 4;
    conv_b<<<dim3((n4 + 255) / 256), blk, 0, stream>>>(x_q,  xq_b,  n4);
    conv_b<<<dim3((n4 + 255) / 256), blk, 0, stream>>>(x_kv, xkv_b, n4);
    conv_t<<<dim3(D_MODEL/32, D_MODEL/32), blk, 0, stream>>>(Wq,  Wq_t,  D_MODEL, D_MODEL);
    conv_t<<<dim3(D_MODEL/32, D_MODEL/32), blk, 0, stream>>>(Wk,  Wk_t,  D_MODEL, D_MODEL);
    conv_t<<<dim3(D_MODEL/32, D_MODEL/32), blk, 0, stream>>>(Wv,  Wv_t,  D_MODEL, D_MODEL);
    conv_t<<<dim3(D_MODEL/32, D_MODEL/32), blk, 0, stream>>>(Wo,  Wo_t,  D_MODEL, D_MODEL);
    conv_t<<<dim3(D_MODEL/32, D_MODEL/32), blk, 0, stream>>>(Ws1, Ws1_t, D_MODEL, D_MODEL);
    conv_t<<<dim3(NKL/32,     D_MODEL/32), blk, 0, stream>>>(Ws2, Ws2_t, D_MODEL, NKL);

    QkvhArgs qa;
    qa.A[0] = xq_b;  qa.W[0] = Wq_t;  qa.bias[0] = bq;  qa.out[0] = Qb;
    qa.A[1] = xkv_b; qa.W[1] = Wk_t;  qa.bias[1] = bk;  qa.out[1] = Kb;
    qa.A[2] = xkv_b; qa.W[2] = Wv_t;  qa.bias[2] = bv;  qa.out[2] = Vb;
    qa.A[3] = xq_b;  qa.W[3] = Ws1_t; qa.bias[3] = bs1; qa.out[3] = hb;
    gemm_qkvh<<<dim3(D_MODEL/128, M_ROWS/128, 4), blk, 0, stream>>>(qa);

    gemm_bf16<<<dim3(NKL/128, M_ROWS/128), blk, 0, stream>>>(hb, Ws2_t, bs2, Sb, NKL, D_MODEL, 0, 1);

    attn_mfma<<<dim3(TQ/64, N_HEADS, B_SZ), blk, 0, stream>>>(Qb, Kb, Vb, Sb, kpm, gate, ctxb);

    gemm_bf16<<<dim3(D_MODEL/128, M_ROWS/128), blk, 0, stream>>>(ctxb, Wo_t, bo, d_out, D_MODEL, D_MODEL, 0, 0);
}

// Round 4
// 235.921 us; speedup vs baseline: 10.0233x; 1.0521x over previous
//
#include <hip/hip_runtime.h>
#include <hip/hip_bf16.h>

#define D_MODEL 1024
#define N_HEADS 16
#define MAX_K_LEN 1024
#define B_SZ 2
#define TQ 1024
#define TK 1024
#define M_ROWS 2048
#define NKL 16384

using bf16x8 = __attribute__((ext_vector_type(8))) short;
using f32x4  = __attribute__((ext_vector_type(4))) float;
using u16x8  = __attribute__((ext_vector_type(8))) unsigned short;

__device__ __forceinline__ unsigned short f2b(float f) {
    unsigned u = __float_as_uint(f);
    u = (u + 0x7FFFu + ((u >> 16) & 1u)) >> 16;
    return (unsigned short)u;
}
__device__ __forceinline__ float b2f(unsigned short u) {
    return __uint_as_float(((unsigned)u) << 16);
}

// async global->LDS, 16B per lane (linear LDS dest: wave base + lane*16)
__device__ __forceinline__ void async_cp16(void* lds, const void* g) {
    __builtin_amdgcn_global_load_lds(
        (__attribute__((address_space(1))) void*)(void*)g,
        (__attribute__((address_space(3))) void*)lds, 16, 0, 0);
}

// chunk swizzle for attention LDS tiles (16B-chunk permutation per 128B row)
__device__ __forceinline__ int xrow(int row) {
    return (row & 7) ^ (((row >> 3) & 3) << 1);
}

// ---------------------------------------------------------------------------
// 256x256 deep-pipelined bf16 MFMA GEMM (8-phase-style, counted vmcnt).
// K must be 1024 (32 K-tiles of BK=32). 512 threads = 8 waves (2M x 4N).
// LDS: 4 buffers x (A 16KB + B 16KB) = 128KB. Prefetch distance 3 tiles.
// C[M,N] = A[M,K] @ Wt[N,K]^T + bias, output bf16.
// ---------------------------------------------------------------------------
__global__ __launch_bounds__(512, 2) void gemm256_bf16(
    const unsigned short* __restrict__ A, const unsigned short* __restrict__ Wt,
    const float* __restrict__ bias, unsigned short* __restrict__ C, int N)
{
    constexpr int K = 1024;
    constexpr int NT = 32;               // K tiles
    __shared__ __align__(16) unsigned short lds[65536];   // 128 KB

    const int tid = threadIdx.x;
    const int lane = tid & 63;
    const int fr = lane & 15, rg = lane >> 4;
    const int w = tid >> 6;
    const int wr = w >> 2, wc = w & 3;

    // XCD-aware bijective swizzle (nwg = 512, divisible by 8)
    const int gx = gridDim.x;
    const int flat = blockIdx.y * gx + blockIdx.x;
    const int cpx = (gx * gridDim.y) >> 3;
    const int f2 = (flat & 7) * cpx + (flat >> 3);
    const int m0g = (f2 / gx) * 256;
    const int n0g = (f2 % gx) * 256;

    // staging source pointers: thread covers 16B chunk (tid&3) of row (tid>>2)
    const int sr = tid >> 2, sc = (tid & 3) * 8;
    const unsigned short* gA0 = A  + (size_t)(m0g + sr) * K + sc;
    const unsigned short* gA1 = A  + (size_t)(m0g + 128 + sr) * K + sc;
    const unsigned short* gB0 = Wt + (size_t)(n0g + sr) * K + sc;
    const unsigned short* gB1 = Wt + (size_t)(n0g + 128 + sr) * K + sc;

    auto stageA = [&](int t) {
        unsigned short* buf = lds + (t & 3) * 16384;
        async_cp16(buf + tid * 8,        gA0 + t * 32);
        async_cp16(buf + 4096 + tid * 8, gA1 + t * 32);
    };
    auto stageB = [&](int t) {
        unsigned short* buf = lds + (t & 3) * 16384 + 8192;
        async_cp16(buf + tid * 8,        gB0 + t * 32);
        async_cp16(buf + 4096 + tid * 8, gB1 + t * 32);
    };

    f32x4 acc[8][4];
#pragma unroll
    for (int i = 0; i < 8; ++i)
#pragma unroll
        for (int j = 0; j < 4; ++j) { f32x4 z = {0.f,0.f,0.f,0.f}; acc[i][j] = z; }

    // prologue: tiles 0,1,2 in flight (12 loads); wait tile 0 (8 remain)
    stageA(0); stageB(0); stageA(1); stageB(1); stageA(2); stageB(2);
    asm volatile("s_waitcnt vmcnt(8)" ::: "memory");
    __builtin_amdgcn_s_barrier();
    __builtin_amdgcn_sched_barrier(0);

    for (int t = 0; t < NT; ++t) {
        const unsigned short* bufA = lds + (t & 3) * 16384;
        const unsigned short* bufB = bufA + 8192;

        // ---- phase 1: frags (B all, A rows 0..63 of wave half) ----
        bf16x8 bfr[4], afr[4];
#pragma unroll
        for (int ni = 0; ni < 4; ++ni)
            bfr[ni] = *(const bf16x8*)(bufB + (wc*64 + ni*16 + fr)*32 + rg*8);
#pragma unroll
        for (int mi = 0; mi < 4; ++mi)
            afr[mi] = *(const bf16x8*)(bufA + (wr*128 + mi*16 + fr)*32 + rg*8);
        if (t + 3 < NT) stageA(t + 3);
        __builtin_amdgcn_s_barrier();
        __builtin_amdgcn_s_setprio(1);
#pragma unroll
        for (int mi = 0; mi < 4; ++mi)
#pragma unroll
            for (int ni = 0; ni < 4; ++ni)
                acc[mi][ni] = __builtin_amdgcn_mfma_f32_16x16x32_bf16(
                    afr[mi], bfr[ni], acc[mi][ni], 0, 0, 0);
        __builtin_amdgcn_s_setprio(0);
        __builtin_amdgcn_s_barrier();

        // ---- phase 2: A rows 64..127 of wave half ----
#pragma unroll
        for (int mi = 0; mi < 4; ++mi)
            afr[mi] = *(const bf16x8*)(bufA + (wr*128 + 64 + mi*16 + fr)*32 + rg*8);
        if (t + 3 < NT) stageB(t + 3);
        __builtin_amdgcn_s_barrier();
        __builtin_amdgcn_s_setprio(1);
#pragma unroll
        for (int mi = 0; mi < 4; ++mi)
#pragma unroll
            for (int ni = 0; ni < 4; ++ni)
                acc[4 + mi][ni] = __builtin_amdgcn_mfma_f32_16x16x32_bf16(
                    afr[mi], bfr[ni], acc[4 + mi][ni], 0, 0, 0);
        __builtin_amdgcn_s_setprio(0);

        // ---- end of tile: counted wait for tile t+1 (never 0 until peel) ----
        if (t < NT - 3)       asm volatile("s_waitcnt vmcnt(8)" ::: "memory");
        else if (t == NT - 3) asm volatile("s_waitcnt vmcnt(4)" ::: "memory");
        else if (t == NT - 2) asm volatile("s_waitcnt vmcnt(0)" ::: "memory");
        __builtin_amdgcn_s_barrier();
        __builtin_amdgcn_sched_barrier(0);
    }

    // ---- epilogue: per-wave LDS transpose for coalesced 16B stores ----
    unsigned short* scr = lds + w * 1024;       // 16 rows x 64 cols per wave
    float bv[4];
#pragma unroll
    for (int ni = 0; ni < 4; ++ni) bv[ni] = bias[n0g + wc*64 + ni*16 + fr];
    const int ro = lane >> 3;
    const int co = (lane & 7) * 8;
#pragma unroll
    for (int mi = 0; mi < 8; ++mi) {
#pragma unroll
        for (int ni = 0; ni < 4; ++ni)
#pragma unroll
            for (int r = 0; r < 4; ++r)
                scr[(rg*4 + r)*64 + ni*16 + fr] = f2b(acc[mi][ni][r] + bv[ni]);
#pragma unroll
        for (int p = 0; p < 2; ++p) {
            const int row = p*8 + ro;
            const u16x8 v = *(const u16x8*)(scr + row*64 + co);
            *(u16x8*)(C + (size_t)(m0g + wr*128 + mi*16 + row) * N + n0g + wc*64 + co) = v;
        }
    }
}

// ---------------------------------------------------------------------------
// bf16 MFMA GEMM core (128x128, BK=32, 4 waves) for the small GEMMs.
// ---------------------------------------------------------------------------
__device__ __forceinline__ void gemm_core(
    const unsigned short* __restrict__ A, const unsigned short* __restrict__ Wt,
    const float* __restrict__ bias, void* __restrict__ Cv,
    unsigned short* As, unsigned short* Bs,
    int N, int K, int m0, int n0, int act, int outbf)
{
    const int tid = threadIdx.x;
    const int lane = tid & 63;
    const int wv = tid >> 6, wr = wv >> 1, wc = wv & 1;

    f32x4 acc[4][4];
#pragma unroll
    for (int i = 0; i < 4; ++i)
#pragma unroll
        for (int j = 0; j < 4; ++j) { f32x4 z = {0.f,0.f,0.f,0.f}; acc[i][j] = z; }

    const int srow = tid >> 2, sch = (tid & 3) * 8;
    const unsigned short* gA0 = A  + (size_t)(m0 + srow) * K + sch;
    const unsigned short* gB0 = Wt + (size_t)(n0 + srow) * K + sch;
    const unsigned short* gA1 = gA0 + (size_t)64 * K;
    const unsigned short* gB1 = gB0 + (size_t)64 * K;
    unsigned short* lA = As + tid * 8;
    unsigned short* lB = Bs + tid * 8;

    const int fr = lane & 15, fk = (lane >> 4) * 8;

    for (int k0 = 0; k0 < K; k0 += 32) {
        async_cp16(lA,        gA0 + k0);
        async_cp16(lA + 2048, gA1 + k0);
        async_cp16(lB,        gB0 + k0);
        async_cp16(lB + 2048, gB1 + k0);
        __syncthreads();

        bf16x8 af[4], bfr[4];
#pragma unroll
        for (int i = 0; i < 4; ++i) {
            af[i]  = *(const bf16x8*)(As + (wr*64 + i*16 + fr)*32 + fk);
            bfr[i] = *(const bf16x8*)(Bs + (wc*64 + i*16 + fr)*32 + fk);
        }
#pragma unroll
        for (int mi = 0; mi < 4; ++mi)
#pragma unroll
            for (int ni = 0; ni < 4; ++ni)
                acc[mi][ni] = __builtin_amdgcn_mfma_f32_16x16x32_bf16(
                    af[mi], bfr[ni], acc[mi][ni], 0, 0, 0);
        __syncthreads();
    }

    const int cr = (lane >> 4) * 4, cc = lane & 15;
#pragma unroll
    for (int mi = 0; mi < 4; ++mi) {
#pragma unroll
        for (int ni = 0; ni < 4; ++ni) {
            const int colx = n0 + wc*64 + ni*16 + cc;
            const float bvv = bias[colx];
#pragma unroll
            for (int r = 0; r < 4; ++r) {
                const int row = m0 + wr*64 + mi*16 + cr + r;
                float c = acc[mi][ni][r] + bvv;
                if (act) c = 0.5f * c * (1.f + erff(c * 0.70710678118654752f));
                if (outbf) ((unsigned short*)Cv)[(size_t)row * N + colx] = f2b(c);
                else       ((float*)Cv)[(size_t)row * N + colx] = c;
            }
        }
    }
}

__global__ __launch_bounds__(256) void gemm_bf16(
    const unsigned short* __restrict__ A, const unsigned short* __restrict__ Wt,
    const float* __restrict__ bias, void* __restrict__ C,
    int N, int K, int act, int outbf)
{
    __shared__ __align__(16) unsigned short As[128*32];
    __shared__ __align__(16) unsigned short Bs[128*32];
    gemm_core(A, Wt, bias, C, As, Bs, N, K, blockIdx.y*128, blockIdx.x*128, act, outbf);
}

struct QkvhArgs {
    const unsigned short* A[4];
    const unsigned short* W[4];
    const float* bias[4];
    void* out[4];
};

__global__ __launch_bounds__(256) void gemm_qkvh(QkvhArgs args) {
    __shared__ __align__(16) unsigned short As[128*32];
    __shared__ __align__(16) unsigned short Bs[128*32];
    const int z = blockIdx.z;
    gemm_core(args.A[z], args.W[z], args.bias[z], args.out[z], As, Bs,
              D_MODEL, D_MODEL, blockIdx.y*128, blockIdx.x*128, (z == 3) ? 1 : 0, 1);
}

// ---------------------------------------------------------------------------
// conversions
// ---------------------------------------------------------------------------
__global__ __launch_bounds__(256) void conv_b(const float* __restrict__ in,
                                              unsigned short* __restrict__ out, int n4) {
    const int i = blockIdx.x * 256 + threadIdx.x;
    if (i < n4) {
        const float4 v = ((const float4*)in)[i];
        ushort4 o; o.x = f2b(v.x); o.y = f2b(v.y); o.z = f2b(v.z); o.w = f2b(v.w);
        ((ushort4*)out)[i] = o;
    }
}

// W[K,N] f32 -> Wt[N,K] bf16, 32x32 tiles
__global__ __launch_bounds__(256) void conv_t(const float* __restrict__ W,
                                              unsigned short* __restrict__ Wt,
                                              int K, int N) {
    __shared__ float T[32][33];
    const int n0 = blockIdx.x * 32, k0 = blockIdx.y * 32;
    const int r = threadIdx.x >> 3, c = (threadIdx.x & 7) * 4;
    const float4 v = *(const float4*)&W[(size_t)(k0 + r) * N + n0 + c];
    T[r][c] = v.x; T[r][c+1] = v.y; T[r][c+2] = v.z; T[r][c+3] = v.w;
    __syncthreads();
    ushort4 o;
    o.x = f2b(T[c][r]); o.y = f2b(T[c+1][r]); o.z = f2b(T[c+2][r]); o.w = f2b(T[c+3][r]);
    *(ushort4*)&Wt[(size_t)(n0 + r) * K + k0 + c] = o;
}

// ---------------------------------------------------------------------------
// MFMA flash attention: block = (q-tile 64, h, b), 4 waves; wave owns 16 q.
// ---------------------------------------------------------------------------
__global__ __launch_bounds__(256) void attn_mfma(
    const unsigned short* __restrict__ Qb, const unsigned short* __restrict__ Kb,
    const unsigned short* __restrict__ Vb, const unsigned short* __restrict__ Sb,
    const int* __restrict__ kpm, const float* __restrict__ gate,
    unsigned short* __restrict__ ctx)
{
    const int bx = blockIdx.x;
    const int q1 = bx >> 1;
    const int qt = (bx & 1) ? q1 : (15 - q1);   // heavy/light interleave
    const int h = blockIdx.y, b = blockIdx.z;
    const int tid = threadIdx.x;
    const int lane = tid & 63;
    const int w = tid >> 6;
    const int col = lane & 15, rg = lane >> 4;

    __shared__ __align__(16) unsigned short Qs[64*64];
    __shared__ __align__(16) unsigned short Ks[64*64];
    __shared__ __align__(16) unsigned short Ss[64*64];
    __shared__ __align__(16) unsigned short Vt[64*64];
    __shared__ __align__(16) unsigned short Pl[4*16*64];

    const float g = 1.f / (1.f + __expf(-gate[h]));
    const float vsc = (1.f - g) * 0.125f;       // (1-g) * dh^-0.5
    const int q0g = qt * 64;

    {   // stage Q (swizzled source, linear LDS)
        const unsigned short* gq = Qb + ((size_t)(b*TQ + q0g)) * D_MODEL + h*64;
        const int r = tid >> 3, cp = tid & 7;
        async_cp16(Qs + tid*8,        gq + (size_t)r*D_MODEL + (cp ^ xrow(r))*8);
        async_cp16(Qs + 2048 + tid*8, gq + (size_t)(r+32)*D_MODEL + (cp ^ xrow(r+32))*8);
    }
    __syncthreads();
    bf16x8 af[2];
    {
        const int qrow = w*16 + col;
        af[0] = *(const bf16x8*)(Qs + qrow*64 + ((rg)     ^ xrow(qrow))*8);
        af[1] = *(const bf16x8*)(Qs + qrow*64 + ((4 + rg) ^ xrow(qrow))*8);
    }

    float mrun[4] = {-INFINITY,-INFINITY,-INFINITY,-INFINITY};
    float lrun[4] = {0.f,0.f,0.f,0.f};
    f32x4 octx[4];
#pragma unroll
    for (int n = 0; n < 4; ++n) { f32x4 z = {0.f,0.f,0.f,0.f}; octx[n] = z; }

    unsigned short* Pw = Pl + w*(16*64);

    for (int kt = 0; kt <= qt; ++kt) {
        __syncthreads();                         // prev tile reads complete
        {   // stage K and S tiles
            const int r = tid >> 3, cp = tid & 7;
            const unsigned short* gk = Kb + ((size_t)(b*TK + kt*64)) * D_MODEL + h*64;
            async_cp16(Ks + tid*8,        gk + (size_t)r*D_MODEL + (cp ^ xrow(r))*8);
            async_cp16(Ks + 2048 + tid*8, gk + (size_t)(r+32)*D_MODEL + (cp ^ xrow(r+32))*8);
            const unsigned short* gs = Sb + ((size_t)(b*TQ + q0g)) * NKL + h*MAX_K_LEN + kt*64;
            async_cp16(Ss + tid*8,        gs + (size_t)r*NKL + (cp ^ xrow(r))*8);
            async_cp16(Ss + 2048 + tid*8, gs + (size_t)(r+32)*NKL + (cp ^ xrow(r+32))*8);
        }
        {   // stage V transposed (reg -> swizzled scalar LDS writes)
            const int vk = tid >> 2, vdc = (tid & 3) * 16;
            const unsigned short* gv = Vb + ((size_t)(b*TK + kt*64 + vk)) * D_MODEL + h*64 + vdc;
            const u16x8 v0 = *(const u16x8*)gv;
            const u16x8 v1 = *(const u16x8*)(gv + 8);
            const int kc = vk >> 3, ke = vk & 7;
#pragma unroll
            for (int j = 0; j < 8; ++j) {
                const int d0 = vdc + j, d1 = vdc + 8 + j;
                Vt[d0*64 + (kc ^ xrow(d0))*8 + ke] = v0[j];
                Vt[d1*64 + (kc ^ xrow(d1))*8 + ke] = v1[j];
            }
        }
        int kvalid[4];
#pragma unroll
        for (int n = 0; n < 4; ++n)
            kvalid[n] = kpm[b*TK + kt*64 + n*16 + col];
        __syncthreads();                         // staging visible

        // --- QK^T: 8 MFMA ---
        f32x4 acc[4];
#pragma unroll
        for (int n = 0; n < 4; ++n) { f32x4 z = {0.f,0.f,0.f,0.f}; acc[n] = z; }
#pragma unroll
        for (int ds = 0; ds < 2; ++ds) {
#pragma unroll
            for (int n = 0; n < 4; ++n) {
                const int kr = n*16 + col;
                const bf16x8 bk = *(const bf16x8*)(Ks + kr*64 + ((ds*4 + rg) ^ xrow(kr))*8);
                acc[n] = __builtin_amdgcn_mfma_f32_16x16x32_bf16(af[ds], bk, acc[n], 0, 0, 0);
            }
        }

        // --- gate + synth + mask, online softmax ---
        const bool diag = (kt == qt);
        float tmax[4] = {-INFINITY,-INFINITY,-INFINITY,-INFINITY};
#pragma unroll
        for (int n = 0; n < 4; ++n) {
            const int kl = n*16 + col;
#pragma unroll
            for (int r = 0; r < 4; ++r) {
                const int ql = w*16 + rg*4 + r;
                const float syn = b2f(Ss[ql*64 + (((kl>>3) ^ xrow(ql)))*8 + (kl&7)]);
                const bool ok = (kvalid[n] > 0) && (!diag || kl <= ql);
                const float sv = ok ? (vsc*acc[n][r] + g*syn) : -INFINITY;
                acc[n][r] = sv;
                tmax[r] = fmaxf(tmax[r], sv);
            }
        }
#pragma unroll
        for (int o = 1; o < 16; o <<= 1) {
#pragma unroll
            for (int r = 0; r < 4; ++r) tmax[r] = fmaxf(tmax[r], __shfl_xor(tmax[r], o));
        }
        float sc[4];
#pragma unroll
        for (int r = 0; r < 4; ++r) {
            const float mn = fmaxf(mrun[r], tmax[r]);
            sc[r] = (mrun[r] == -INFINITY) ? 0.f : __expf(mrun[r] - mn);
            mrun[r] = mn;
        }
        float tsum[4] = {0.f,0.f,0.f,0.f};
#pragma unroll
        for (int n = 0; n < 4; ++n)
#pragma unroll
            for (int r = 0; r < 4; ++r) {
                const float p = (acc[n][r] == -INFINITY) ? 0.f : __expf(acc[n][r] - mrun[r]);
                acc[n][r] = p;
                tsum[r] += p;
            }
#pragma unroll
        for (int o = 1; o < 16; o <<= 1) {
#pragma unroll
            for (int r = 0; r < 4; ++r) tsum[r] += __shfl_xor(tsum[r], o);
        }
#pragma unroll
        for (int r = 0; r < 4; ++r) lrun[r] = lrun[r]*sc[r] + tsum[r];
#pragma unroll
        for (int n = 0; n < 4; ++n)
#pragma unroll
            for (int r = 0; r < 4; ++r) octx[n][r] *= sc[r];

        // --- P -> per-wave LDS (bf16, swizzled) ---
#pragma unroll
        for (int n = 0; n < 4; ++n) {
            const int kc = n*16 + col;
#pragma unroll
            for (int r = 0; r < 4; ++r) {
                const int q = rg*4 + r;
                Pw[q*64 + (((kc>>3) ^ xrow(q)))*8 + (kc&7)] = f2b(acc[n][r]);
            }
        }

        // --- PV: 8 MFMA ---
#pragma unroll
        for (int ks = 0; ks < 2; ++ks) {
            const bf16x8 pa = *(const bf16x8*)(Pw + col*64 + ((ks*4 + rg) ^ xrow(col))*8);
#pragma unroll
            for (int n = 0; n < 4; ++n) {
                const int d = n*16 + col;
                const bf16x8 vv = *(const bf16x8*)(Vt + d*64 + ((ks*4 + rg) ^ xrow(d))*8);
                octx[n] = __builtin_amdgcn_mfma_f32_16x16x32_bf16(pa, vv, octx[n], 0, 0, 0);
            }
        }
    }

    // epilogue
    float inv[4];
#pragma unroll
    for (int r = 0; r < 4; ++r) inv[r] = (lrun[r] > 0.f) ? 1.f/lrun[r] : 0.f;
#pragma unroll
    for (int n = 0; n < 4; ++n)
#pragma unroll
        for (int r = 0; r < 4; ++r) {
            const size_t row = (size_t)(b*TQ + q0g + w*16 + rg*4 + r);
            ctx[row*D_MODEL + h*64 + n*16 + col] = f2b(octx[n][r]*inv[r]);
        }
}

// ---------------------------------------------------------------------------
extern "C" void kernel_launch(void* const* d_in, const int* in_sizes, int n_in,
                              void* d_out, int out_size, void* d_ws, size_t ws_size,
                              hipStream_t stream) {
    const float* x_q  = (const float*)d_in[0];
    const float* x_kv = (const float*)d_in[1];
    const int*   kpm  = (const int*)d_in[2];
    const float* Wq  = (const float*)d_in[3];  const float* bq  = (const float*)d_in[4];
    const float* Wk  = (const float*)d_in[5];  const float* bk  = (const float*)d_in[6];
    const float* Wv  = (const float*)d_in[7];  const float* bv  = (const float*)d_in[8];
    const float* Wo  = (const float*)d_in[9];  const float* bo  = (const float*)d_in[10];
    const float* Ws1 = (const float*)d_in[11]; const float* bs1 = (const float*)d_in[12];
    const float* Ws2 = (const float*)d_in[13]; const float* bs2 = (const float*)d_in[14];
    const float* gate = (const float*)d_in[15];

    char* ws = (char*)d_ws;
    const size_t MB = 1024ull * 1024ull;
    // Sb (64MB) overlays xq_b/xkv_b (dead before Sb is written)
    unsigned short* Sb    = (unsigned short*)ws;
    unsigned short* xq_b  = (unsigned short*)ws;               // 4MB
    unsigned short* xkv_b = (unsigned short*)(ws + 4*MB);      // 4MB
    size_t off = 64*MB;
    unsigned short* Wq_t  = (unsigned short*)(ws + off); off += 2*MB;
    unsigned short* Wk_t  = (unsigned short*)(ws + off); off += 2*MB;
    unsigned short* Wv_t  = (unsigned short*)(ws + off); off += 2*MB;
    unsigned short* Wo_t  = (unsigned short*)(ws + off); off += 2*MB;
    unsigned short* Ws1_t = (unsigned short*)(ws + off); off += 2*MB;
    unsigned short* Ws2_t = (unsigned short*)(ws + off); off += 32*MB;
    unsigned short* Qb    = (unsigned short*)(ws + off); off += 4*MB;
    unsigned short* Kb    = (unsigned short*)(ws + off); off += 4*MB;
    unsigned short* Vb    = (unsigned short*)(ws + off); off += 4*MB;
    unsigned short* hb    = (unsigned short*)(ws + off); off += 4*MB;
    unsigned short* ctxb  = (unsigned short*)(ws + off); off += 4*MB;

    dim3 blk(256);
    const int n4 = M_ROWS * D_MODEL / 4;
    conv_b<<<dim3((n4 + 255) / 256), blk, 0, stream>>>(x_q,  xq_b,  n4);
    conv_b<<<dim3((n4 + 255) / 256), blk, 0, stream>>>(x_kv, xkv_b, n4);
    conv_t<<<dim3(D_MODEL/32, D_MODEL/32), blk, 0, stream>>>(Wq,  Wq_t,  D_MODEL, D_MODEL);
    conv_t<<<dim3(D_MODEL/32, D_MODEL/32), blk, 0, stream>>>(Wk,  Wk_t,  D_MODEL, D_MODEL);
    conv_t<<<dim3(D_MODEL/32, D_MODEL/32), blk, 0, stream>>>(Wv,  Wv_t,  D_MODEL, D_MODEL);
    conv_t<<<dim3(D_MODEL/32, D_MODEL/32), blk, 0, stream>>>(Wo,  Wo_t,  D_MODEL, D_MODEL);
    conv_t<<<dim3(D_MODEL/32, D_MODEL/32), blk, 0, stream>>>(Ws1, Ws1_t, D_MODEL, D_MODEL);
    conv_t<<<dim3(NKL/32,     D_MODEL/32), blk, 0, stream>>>(Ws2, Ws2_t, D_MODEL, NKL);

    QkvhArgs qa;
    qa.A[0] = xq_b;  qa.W[0] = Wq_t;  qa.bias[0] = bq;  qa.out[0] = Qb;
    qa.A[1] = xkv_b; qa.W[1] = Wk_t;  qa.bias[1] = bk;  qa.out[1] = Kb;
    qa.A[2] = xkv_b; qa.W[2] = Wv_t;  qa.bias[2] = bv;  qa.out[2] = Vb;
    qa.A[3] = xq_b;  qa.W[3] = Ws1_t; qa.bias[3] = bs1; qa.out[3] = hb;
    gemm_qkvh<<<dim3(D_MODEL/128, M_ROWS/128, 4), blk, 0, stream>>>(qa);

    // big synth GEMM: 256x256 deep-pipelined kernel, grid (N/256, M/256) = (64, 8)
    gemm256_bf16<<<dim3(NKL/256, M_ROWS/256), dim3(512), 0, stream>>>(hb, Ws2_t, bs2, Sb, NKL);

    attn_mfma<<<dim3(TQ/64, N_HEADS, B_SZ), blk, 0, stream>>>(Qb, Kb, Vb, Sb, kpm, gate, ctxb);

    gemm_bf16<<<dim3(D_MODEL/128, M_ROWS/128), blk, 0, stream>>>(ctxb, Wo_t, bo, d_out, D_MODEL, D_MODEL, 0, 0);
}

// Round 5
// 222.750 us; speedup vs baseline: 10.6160x; 1.0591x over previous
//
#include <hip/hip_runtime.h>
#include <hip/hip_bf16.h>

#define D_MODEL 1024
#define N_HEADS 16
#define MAX_K_LEN 1024
#define B_SZ 2
#define TQ 1024
#define TK 1024
#define M_ROWS 2048
#define NKL 16384

using bf16x8 = __attribute__((ext_vector_type(8))) short;
using f32x4  = __attribute__((ext_vector_type(4))) float;
using u16x8  = __attribute__((ext_vector_type(8))) unsigned short;

__device__ __forceinline__ unsigned short f2b(float f) {
    unsigned u = __float_as_uint(f);
    u = (u + 0x7FFFu + ((u >> 16) & 1u)) >> 16;
    return (unsigned short)u;
}
__device__ __forceinline__ float b2f(unsigned short u) {
    return __uint_as_float(((unsigned)u) << 16);
}

// async global->LDS, 16B per lane (linear LDS dest: wave base + lane*16)
__device__ __forceinline__ void async_cp16(void* lds, const void* g) {
    __builtin_amdgcn_global_load_lds(
        (__attribute__((address_space(1))) void*)(void*)g,
        (__attribute__((address_space(3))) void*)lds, 16, 0, 0);
}

// chunk swizzle for attention LDS tiles (16B-chunk permutation per 128B row)
__device__ __forceinline__ int xrow(int row) {
    return (row & 7) ^ (((row >> 3) & 3) << 1);
}

// GEMM tile swizzle: 16B chunk c of row r stored at slot c ^ ((r>>1)&3).
// Spreads any 16 consecutive-row lane group uniformly over the 8 16B-slots
// per 128B (2 touches/slot = b128 minimum) -> conflict-free fragment reads.

// ---------------------------------------------------------------------------
// 256x256 deep-pipelined bf16 MFMA GEMM (8-phase-style, counted vmcnt).
// K must be 1024 (32 K-tiles of BK=32). 512 threads = 8 waves (2M x 4N).
// LDS: 4 buffers x (A 16KB + B 16KB) = 128 KB. Prefetch distance 3 tiles.
// C[M,N] = A[M,K] @ Wt[N,K]^T + bias, output bf16.
// ---------------------------------------------------------------------------
__global__ __launch_bounds__(512, 2) void gemm256_bf16(
    const unsigned short* __restrict__ A, const unsigned short* __restrict__ Wt,
    const float* __restrict__ bias, unsigned short* __restrict__ C, int N)
{
    constexpr int K = 1024;
    constexpr int NT = 32;               // K tiles
    __shared__ __align__(16) unsigned short lds[65536];   // 128 KB

    const int tid = threadIdx.x;
    const int lane = tid & 63;
    const int fr = lane & 15, rg = lane >> 4;
    const int w = tid >> 6;
    const int wr = w >> 2, wc = w & 3;

    // XCD-aware bijective swizzle (nwg = 512, divisible by 8)
    const int gx = gridDim.x;
    const int flat = blockIdx.y * gx + blockIdx.x;
    const int cpx = (gx * gridDim.y) >> 3;
    const int f2 = (flat & 7) * cpx + (flat >> 3);
    const int m0g = (f2 / gx) * 256;
    const int n0g = (f2 % gx) * 256;

    // staging: thread covers row sr, LDS chunk (tid&3); global source chunk is
    // inverse-swizzled so LDS slot c holds global chunk c ^ ((sr>>1)&3).
    const int sr = tid >> 2;
    const int sc = (((tid & 3) ^ ((sr >> 1) & 3))) * 8;
    const unsigned short* gA0 = A  + (size_t)(m0g + sr) * K + sc;
    const unsigned short* gA1 = A  + (size_t)(m0g + 128 + sr) * K + sc;
    const unsigned short* gB0 = Wt + (size_t)(n0g + sr) * K + sc;
    const unsigned short* gB1 = Wt + (size_t)(n0g + 128 + sr) * K + sc;

    auto stageA = [&](int t) {
        unsigned short* buf = lds + (t & 3) * 16384;
        async_cp16(buf + tid * 8,        gA0 + t * 32);
        async_cp16(buf + 4096 + tid * 8, gA1 + t * 32);
    };
    auto stageB = [&](int t) {
        unsigned short* buf = lds + (t & 3) * 16384 + 8192;
        async_cp16(buf + tid * 8,        gB0 + t * 32);
        async_cp16(buf + 4096 + tid * 8, gB1 + t * 32);
    };

    f32x4 acc[8][4];
#pragma unroll
    for (int i = 0; i < 8; ++i)
#pragma unroll
        for (int j = 0; j < 4; ++j) { f32x4 z = {0.f,0.f,0.f,0.f}; acc[i][j] = z; }

    // fragment-read chunk: rg ^ ((row>>1)&3); row>>1 & 3 == (fr>>1)&3 for all frags
    const int fko = (rg ^ ((fr >> 1) & 3)) * 8;

    // prologue: tiles 0,1,2 in flight (12 loads); wait tile 0 (8 remain)
    stageA(0); stageB(0); stageA(1); stageB(1); stageA(2); stageB(2);
    asm volatile("s_waitcnt vmcnt(8)" ::: "memory");
    __builtin_amdgcn_s_barrier();
    __builtin_amdgcn_sched_barrier(0);

    for (int t = 0; t < NT; ++t) {
        const unsigned short* bufA = lds + (t & 3) * 16384;
        const unsigned short* bufB = bufA + 8192;

        // ---- phase 1: frags (B all, A rows 0..63 of wave half) ----
        bf16x8 bfr[4], afr[4];
#pragma unroll
        for (int ni = 0; ni < 4; ++ni)
            bfr[ni] = *(const bf16x8*)(bufB + (wc*64 + ni*16 + fr)*32 + fko);
#pragma unroll
        for (int mi = 0; mi < 4; ++mi)
            afr[mi] = *(const bf16x8*)(bufA + (wr*128 + mi*16 + fr)*32 + fko);
        if (t + 3 < NT) stageA(t + 3);
        __builtin_amdgcn_s_barrier();
        __builtin_amdgcn_s_setprio(1);
#pragma unroll
        for (int mi = 0; mi < 4; ++mi)
#pragma unroll
            for (int ni = 0; ni < 4; ++ni)
                acc[mi][ni] = __builtin_amdgcn_mfma_f32_16x16x32_bf16(
                    afr[mi], bfr[ni], acc[mi][ni], 0, 0, 0);
        __builtin_amdgcn_s_setprio(0);
        __builtin_amdgcn_s_barrier();

        // ---- phase 2: A rows 64..127 of wave half ----
#pragma unroll
        for (int mi = 0; mi < 4; ++mi)
            afr[mi] = *(const bf16x8*)(bufA + (wr*128 + 64 + mi*16 + fr)*32 + fko);
        if (t + 3 < NT) stageB(t + 3);
        __builtin_amdgcn_s_barrier();
        __builtin_amdgcn_s_setprio(1);
#pragma unroll
        for (int mi = 0; mi < 4; ++mi)
#pragma unroll
            for (int ni = 0; ni < 4; ++ni)
                acc[4 + mi][ni] = __builtin_amdgcn_mfma_f32_16x16x32_bf16(
                    afr[mi], bfr[ni], acc[4 + mi][ni], 0, 0, 0);
        __builtin_amdgcn_s_setprio(0);

        // ---- end of tile: counted wait for tile t+1 (never 0 until peel) ----
        if (t < NT - 3)       asm volatile("s_waitcnt vmcnt(8)" ::: "memory");
        else if (t == NT - 3) asm volatile("s_waitcnt vmcnt(4)" ::: "memory");
        else if (t == NT - 2) asm volatile("s_waitcnt vmcnt(0)" ::: "memory");
        __builtin_amdgcn_s_barrier();
        __builtin_amdgcn_sched_barrier(0);
    }

    // ---- epilogue: per-wave LDS transpose for coalesced 16B stores ----
    unsigned short* scr = lds + w * 1024;       // 16 rows x 64 cols per wave
    float bv[4];
#pragma unroll
    for (int ni = 0; ni < 4; ++ni) bv[ni] = bias[n0g + wc*64 + ni*16 + fr];
    const int ro = lane >> 3;
    const int co = (lane & 7) * 8;
#pragma unroll
    for (int mi = 0; mi < 8; ++mi) {
#pragma unroll
        for (int ni = 0; ni < 4; ++ni)
#pragma unroll
            for (int r = 0; r < 4; ++r)
                scr[(rg*4 + r)*64 + ni*16 + fr] = f2b(acc[mi][ni][r] + bv[ni]);
#pragma unroll
        for (int p = 0; p < 2; ++p) {
            const int row = p*8 + ro;
            const u16x8 v = *(const u16x8*)(scr + row*64 + co);
            *(u16x8*)(C + (size_t)(m0g + wr*128 + mi*16 + row) * N + n0g + wc*64 + co) = v;
        }
    }
}

// ---------------------------------------------------------------------------
// bf16 MFMA GEMM core (128x128, BK=32, 4 waves) for the small GEMMs.
// Same chunk swizzle as gemm256.
// ---------------------------------------------------------------------------
__device__ __forceinline__ void gemm_core(
    const unsigned short* __restrict__ A, const unsigned short* __restrict__ Wt,
    const float* __restrict__ bias, void* __restrict__ Cv,
    unsigned short* As, unsigned short* Bs,
    int N, int K, int m0, int n0, int act, int outbf)
{
    const int tid = threadIdx.x;
    const int lane = tid & 63;
    const int wv = tid >> 6, wr = wv >> 1, wc = wv & 1;

    f32x4 acc[4][4];
#pragma unroll
    for (int i = 0; i < 4; ++i)
#pragma unroll
        for (int j = 0; j < 4; ++j) { f32x4 z = {0.f,0.f,0.f,0.f}; acc[i][j] = z; }

    const int srow = tid >> 2;
    const int sch = (((tid & 3) ^ ((srow >> 1) & 3))) * 8;
    const unsigned short* gA0 = A  + (size_t)(m0 + srow) * K + sch;
    const unsigned short* gB0 = Wt + (size_t)(n0 + srow) * K + sch;
    const unsigned short* gA1 = gA0 + (size_t)64 * K;
    const unsigned short* gB1 = gB0 + (size_t)64 * K;
    unsigned short* lA = As + tid * 8;
    unsigned short* lB = Bs + tid * 8;

    const int fr = lane & 15, rg = lane >> 4;
    const int fko = (rg ^ ((fr >> 1) & 3)) * 8;

    for (int k0 = 0; k0 < K; k0 += 32) {
        async_cp16(lA,        gA0 + k0);
        async_cp16(lA + 2048, gA1 + k0);
        async_cp16(lB,        gB0 + k0);
        async_cp16(lB + 2048, gB1 + k0);
        __syncthreads();

        bf16x8 af[4], bfr[4];
#pragma unroll
        for (int i = 0; i < 4; ++i) {
            af[i]  = *(const bf16x8*)(As + (wr*64 + i*16 + fr)*32 + fko);
            bfr[i] = *(const bf16x8*)(Bs + (wc*64 + i*16 + fr)*32 + fko);
        }
#pragma unroll
        for (int mi = 0; mi < 4; ++mi)
#pragma unroll
            for (int ni = 0; ni < 4; ++ni)
                acc[mi][ni] = __builtin_amdgcn_mfma_f32_16x16x32_bf16(
                    af[mi], bfr[ni], acc[mi][ni], 0, 0, 0);
        __syncthreads();
    }

    const int cr = (lane >> 4) * 4, cc = lane & 15;
#pragma unroll
    for (int mi = 0; mi < 4; ++mi) {
#pragma unroll
        for (int ni = 0; ni < 4; ++ni) {
            const int colx = n0 + wc*64 + ni*16 + cc;
            const float bvv = bias[colx];
#pragma unroll
            for (int r = 0; r < 4; ++r) {
                const int row = m0 + wr*64 + mi*16 + cr + r;
                float c = acc[mi][ni][r] + bvv;
                if (act) c = 0.5f * c * (1.f + erff(c * 0.70710678118654752f));
                if (outbf) ((unsigned short*)Cv)[(size_t)row * N + colx] = f2b(c);
                else       ((float*)Cv)[(size_t)row * N + colx] = c;
            }
        }
    }
}

__global__ __launch_bounds__(256) void gemm_bf16(
    const unsigned short* __restrict__ A, const unsigned short* __restrict__ Wt,
    const float* __restrict__ bias, void* __restrict__ C,
    int N, int K, int act, int outbf)
{
    __shared__ __align__(16) unsigned short As[128*32];
    __shared__ __align__(16) unsigned short Bs[128*32];
    gemm_core(A, Wt, bias, C, As, Bs, N, K, blockIdx.y*128, blockIdx.x*128, act, outbf);
}

struct QkvhArgs {
    const unsigned short* A[4];
    const unsigned short* W[4];
    const float* bias[4];
    void* out[4];
};

__global__ __launch_bounds__(256) void gemm_qkvh(QkvhArgs args) {
    __shared__ __align__(16) unsigned short As[128*32];
    __shared__ __align__(16) unsigned short Bs[128*32];
    const int z = blockIdx.z;
    gemm_core(args.A[z], args.W[z], args.bias[z], args.out[z], As, Bs,
              D_MODEL, D_MODEL, blockIdx.y*128, blockIdx.x*128, (z == 3) ? 1 : 0, 1);
}

// ---------------------------------------------------------------------------
// fused prep: all f32->bf16 conversions + weight transposes in ONE launch.
// segments: [0,2048) xq conv, [2048,4096) xkv conv,
//           [4096,4096+5*1024) five 1024x1024 transposes,
//           [9216, 9216+16384) Ws2 transpose (K=1024, N=16384).
// ---------------------------------------------------------------------------
struct PrepArgs {
    const float* xq; const float* xkv;
    unsigned short* xq_b; unsigned short* xkv_b;
    const float* W[6]; unsigned short* Wt[6]; int Nw[6];
};

__global__ __launch_bounds__(256) void prep_all(PrepArgs p) {
    __shared__ float T[32][33];
    int id = blockIdx.x;
    if (id < 4096) {
        const float* src = (id < 2048) ? p.xq : p.xkv;
        unsigned short* dst = (id < 2048) ? p.xq_b : p.xkv_b;
        const int i = (id & 2047) * 256 + threadIdx.x;
        const float4 v = ((const float4*)src)[i];
        ushort4 o; o.x = f2b(v.x); o.y = f2b(v.y); o.z = f2b(v.z); o.w = f2b(v.w);
        ((ushort4*)dst)[i] = o;
        return;
    }
    id -= 4096;
    int seg, lb;
    if (id < 5120) { seg = id >> 10; lb = id & 1023; }
    else           { seg = 5;        lb = id - 5120; }
    const int N = p.Nw[seg];
    const int nx = N >> 5;
    const int bx = lb % nx, by = lb / nx;
    const int n0 = bx * 32, k0 = by * 32;
    const float* W = p.W[seg];
    unsigned short* Wt = p.Wt[seg];
    const int r = threadIdx.x >> 3, c = (threadIdx.x & 7) * 4;
    const float4 v = *(const float4*)&W[(size_t)(k0 + r) * N + n0 + c];
    T[r][c] = v.x; T[r][c+1] = v.y; T[r][c+2] = v.z; T[r][c+3] = v.w;
    __syncthreads();
    ushort4 o;
    o.x = f2b(T[c][r]); o.y = f2b(T[c+1][r]); o.z = f2b(T[c+2][r]); o.w = f2b(T[c+3][r]);
    *(ushort4*)&Wt[(size_t)(n0 + r) * D_MODEL + k0 + c] = o;
}

// ---------------------------------------------------------------------------
// MFMA flash attention: block = (q-tile 64, h, b), 4 waves; wave owns 16 q.
// ---------------------------------------------------------------------------
__global__ __launch_bounds__(256) void attn_mfma(
    const unsigned short* __restrict__ Qb, const unsigned short* __restrict__ Kb,
    const unsigned short* __restrict__ Vb, const unsigned short* __restrict__ Sb,
    const int* __restrict__ kpm, const float* __restrict__ gate,
    unsigned short* __restrict__ ctx)
{
    const int bx = blockIdx.x;
    const int q1 = bx >> 1;
    const int qt = (bx & 1) ? q1 : (15 - q1);   // heavy/light interleave
    const int h = blockIdx.y, b = blockIdx.z;
    const int tid = threadIdx.x;
    const int lane = tid & 63;
    const int w = tid >> 6;
    const int col = lane & 15, rg = lane >> 4;

    __shared__ __align__(16) unsigned short Qs[64*64];
    __shared__ __align__(16) unsigned short Ks[64*64];
    __shared__ __align__(16) unsigned short Ss[64*64];
    __shared__ __align__(16) unsigned short Vt[64*64];
    __shared__ __align__(16) unsigned short Pl[4*16*64];

    const float g = 1.f / (1.f + __expf(-gate[h]));
    const float vsc = (1.f - g) * 0.125f;       // (1-g) * dh^-0.5
    const int q0g = qt * 64;

    {   // stage Q (swizzled source, linear LDS)
        const unsigned short* gq = Qb + ((size_t)(b*TQ + q0g)) * D_MODEL + h*64;
        const int r = tid >> 3, cp = tid & 7;
        async_cp16(Qs + tid*8,        gq + (size_t)r*D_MODEL + (cp ^ xrow(r))*8);
        async_cp16(Qs + 2048 + tid*8, gq + (size_t)(r+32)*D_MODEL + (cp ^ xrow(r+32))*8);
    }
    __syncthreads();
    bf16x8 af[2];
    {
        const int qrow = w*16 + col;
        af[0] = *(const bf16x8*)(Qs + qrow*64 + ((rg)     ^ xrow(qrow))*8);
        af[1] = *(const bf16x8*)(Qs + qrow*64 + ((4 + rg) ^ xrow(qrow))*8);
    }

    float mrun[4] = {-INFINITY,-INFINITY,-INFINITY,-INFINITY};
    float lrun[4] = {0.f,0.f,0.f,0.f};
    f32x4 octx[4];
#pragma unroll
    for (int n = 0; n < 4; ++n) { f32x4 z = {0.f,0.f,0.f,0.f}; octx[n] = z; }

    unsigned short* Pw = Pl + w*(16*64);

    for (int kt = 0; kt <= qt; ++kt) {
        __syncthreads();                         // prev tile reads complete
        {   // stage K and S tiles
            const int r = tid >> 3, cp = tid & 7;
            const unsigned short* gk = Kb + ((size_t)(b*TK + kt*64)) * D_MODEL + h*64;
            async_cp16(Ks + tid*8,        gk + (size_t)r*D_MODEL + (cp ^ xrow(r))*8);
            async_cp16(Ks + 2048 + tid*8, gk + (size_t)(r+32)*D_MODEL + (cp ^ xrow(r+32))*8);
            const unsigned short* gs = Sb + ((size_t)(b*TQ + q0g)) * NKL + h*MAX_K_LEN + kt*64;
            async_cp16(Ss + tid*8,        gs + (size_t)r*NKL + (cp ^ xrow(r))*8);
            async_cp16(Ss + 2048 + tid*8, gs + (size_t)(r+32)*NKL + (cp ^ xrow(r+32))*8);
        }
        {   // stage V transposed (reg -> swizzled scalar LDS writes)
            const int vk = tid >> 2, vdc = (tid & 3) * 16;
            const unsigned short* gv = Vb + ((size_t)(b*TK + kt*64 + vk)) * D_MODEL + h*64 + vdc;
            const u16x8 v0 = *(const u16x8*)gv;
            const u16x8 v1 = *(const u16x8*)(gv + 8);
            const int kc = vk >> 3, ke = vk & 7;
#pragma unroll
            for (int j = 0; j < 8; ++j) {
                const int d0 = vdc + j, d1 = vdc + 8 + j;
                Vt[d0*64 + (kc ^ xrow(d0))*8 + ke] = v0[j];
                Vt[d1*64 + (kc ^ xrow(d1))*8 + ke] = v1[j];
            }
        }
        int kvalid[4];
#pragma unroll
        for (int n = 0; n < 4; ++n)
            kvalid[n] = kpm[b*TK + kt*64 + n*16 + col];
        __syncthreads();                         // staging visible

        // --- QK^T: 8 MFMA ---
        f32x4 acc[4];
#pragma unroll
        for (int n = 0; n < 4; ++n) { f32x4 z = {0.f,0.f,0.f,0.f}; acc[n] = z; }
#pragma unroll
        for (int ds = 0; ds < 2; ++ds) {
#pragma unroll
            for (int n = 0; n < 4; ++n) {
                const int kr = n*16 + col;
                const bf16x8 bk = *(const bf16x8*)(Ks + kr*64 + ((ds*4 + rg) ^ xrow(kr))*8);
                acc[n] = __builtin_amdgcn_mfma_f32_16x16x32_bf16(af[ds], bk, acc[n], 0, 0, 0);
            }
        }

        // --- gate + synth + mask, online softmax ---
        const bool diag = (kt == qt);
        float tmax[4] = {-INFINITY,-INFINITY,-INFINITY,-INFINITY};
#pragma unroll
        for (int n = 0; n < 4; ++n) {
            const int kl = n*16 + col;
#pragma unroll
            for (int r = 0; r < 4; ++r) {
                const int ql = w*16 + rg*4 + r;
                const float syn = b2f(Ss[ql*64 + (((kl>>3) ^ xrow(ql)))*8 + (kl&7)]);
                const bool ok = (kvalid[n] > 0) && (!diag || kl <= ql);
                const float sv = ok ? (vsc*acc[n][r] + g*syn) : -INFINITY;
                acc[n][r] = sv;
                tmax[r] = fmaxf(tmax[r], sv);
            }
        }
#pragma unroll
        for (int o = 1; o < 16; o <<= 1) {
#pragma unroll
            for (int r = 0; r < 4; ++r) tmax[r] = fmaxf(tmax[r], __shfl_xor(tmax[r], o));
        }
        float sc[4];
#pragma unroll
        for (int r = 0; r < 4; ++r) {
            const float mn = fmaxf(mrun[r], tmax[r]);
            sc[r] = (mrun[r] == -INFINITY) ? 0.f : __expf(mrun[r] - mn);
            mrun[r] = mn;
        }
        float tsum[4] = {0.f,0.f,0.f,0.f};
#pragma unroll
        for (int n = 0; n < 4; ++n)
#pragma unroll
            for (int r = 0; r < 4; ++r) {
                const float p = (acc[n][r] == -INFINITY) ? 0.f : __expf(acc[n][r] - mrun[r]);
                acc[n][r] = p;
                tsum[r] += p;
            }
#pragma unroll
        for (int o = 1; o < 16; o <<= 1) {
#pragma unroll
            for (int r = 0; r < 4; ++r) tsum[r] += __shfl_xor(tsum[r], o);
        }
#pragma unroll
        for (int r = 0; r < 4; ++r) lrun[r] = lrun[r]*sc[r] + tsum[r];
#pragma unroll
        for (int n = 0; n < 4; ++n)
#pragma unroll
            for (int r = 0; r < 4; ++r) octx[n][r] *= sc[r];

        // --- P -> per-wave LDS (bf16, swizzled) ---
#pragma unroll
        for (int n = 0; n < 4; ++n) {
            const int kc = n*16 + col;
#pragma unroll
            for (int r = 0; r < 4; ++r) {
                const int q = rg*4 + r;
                Pw[q*64 + (((kc>>3) ^ xrow(q)))*8 + (kc&7)] = f2b(acc[n][r]);
            }
        }

        // --- PV: 8 MFMA ---
#pragma unroll
        for (int ks = 0; ks < 2; ++ks) {
            const bf16x8 pa = *(const bf16x8*)(Pw + col*64 + ((ks*4 + rg) ^ xrow(col))*8);
#pragma unroll
            for (int n = 0; n < 4; ++n) {
                const int d = n*16 + col;
                const bf16x8 vv = *(const bf16x8*)(Vt + d*64 + ((ks*4 + rg) ^ xrow(d))*8);
                octx[n] = __builtin_amdgcn_mfma_f32_16x16x32_bf16(pa, vv, octx[n], 0, 0, 0);
            }
        }
    }

    // epilogue
    float inv[4];
#pragma unroll
    for (int r = 0; r < 4; ++r) inv[r] = (lrun[r] > 0.f) ? 1.f/lrun[r] : 0.f;
#pragma unroll
    for (int n = 0; n < 4; ++n)
#pragma unroll
        for (int r = 0; r < 4; ++r) {
            const size_t row = (size_t)(b*TQ + q0g + w*16 + rg*4 + r);
            ctx[row*D_MODEL + h*64 + n*16 + col] = f2b(octx[n][r]*inv[r]);
        }
}

// ---------------------------------------------------------------------------
extern "C" void kernel_launch(void* const* d_in, const int* in_sizes, int n_in,
                              void* d_out, int out_size, void* d_ws, size_t ws_size,
                              hipStream_t stream) {
    const float* x_q  = (const float*)d_in[0];
    const float* x_kv = (const float*)d_in[1];
    const int*   kpm  = (const int*)d_in[2];
    const float* Wq  = (const float*)d_in[3];  const float* bq  = (const float*)d_in[4];
    const float* Wk  = (const float*)d_in[5];  const float* bk  = (const float*)d_in[6];
    const float* Wv  = (const float*)d_in[7];  const float* bv  = (const float*)d_in[8];
    const float* Wo  = (const float*)d_in[9];  const float* bo  = (const float*)d_in[10];
    const float* Ws1 = (const float*)d_in[11]; const float* bs1 = (const float*)d_in[12];
    const float* Ws2 = (const float*)d_in[13]; const float* bs2 = (const float*)d_in[14];
    const float* gate = (const float*)d_in[15];

    char* ws = (char*)d_ws;
    const size_t MB = 1024ull * 1024ull;
    // Sb (64MB) overlays xq_b/xkv_b (dead before Sb is written)
    unsigned short* Sb    = (unsigned short*)ws;
    unsigned short* xq_b  = (unsigned short*)ws;               // 4MB
    unsigned short* xkv_b = (unsigned short*)(ws + 4*MB);      // 4MB
    size_t off = 64*MB;
    unsigned short* Wq_t  = (unsigned short*)(ws + off); off += 2*MB;
    unsigned short* Wk_t  = (unsigned short*)(ws + off); off += 2*MB;
    unsigned short* Wv_t  = (unsigned short*)(ws + off); off += 2*MB;
    unsigned short* Wo_t  = (unsigned short*)(ws + off); off += 2*MB;
    unsigned short* Ws1_t = (unsigned short*)(ws + off); off += 2*MB;
    unsigned short* Ws2_t = (unsigned short*)(ws + off); off += 32*MB;
    unsigned short* Qb    = (unsigned short*)(ws + off); off += 4*MB;
    unsigned short* Kb    = (unsigned short*)(ws + off); off += 4*MB;
    unsigned short* Vb    = (unsigned short*)(ws + off); off += 4*MB;
    unsigned short* hb    = (unsigned short*)(ws + off); off += 4*MB;
    unsigned short* ctxb  = (unsigned short*)(ws + off); off += 4*MB;

    dim3 blk(256);

    PrepArgs pa;
    pa.xq = x_q; pa.xkv = x_kv; pa.xq_b = xq_b; pa.xkv_b = xkv_b;
    pa.W[0] = Wq;  pa.Wt[0] = Wq_t;  pa.Nw[0] = D_MODEL;
    pa.W[1] = Wk;  pa.Wt[1] = Wk_t;  pa.Nw[1] = D_MODEL;
    pa.W[2] = Wv;  pa.Wt[2] = Wv_t;  pa.Nw[2] = D_MODEL;
    pa.W[3] = Wo;  pa.Wt[3] = Wo_t;  pa.Nw[3] = D_MODEL;
    pa.W[4] = Ws1; pa.Wt[4] = Ws1_t; pa.Nw[4] = D_MODEL;
    pa.W[5] = Ws2; pa.Wt[5] = Ws2_t; pa.Nw[5] = NKL;
    prep_all<<<dim3(25600), blk, 0, stream>>>(pa);

    QkvhArgs qa;
    qa.A[0] = xq_b;  qa.W[0] = Wq_t;  qa.bias[0] = bq;  qa.out[0] = Qb;
    qa.A[1] = xkv_b; qa.W[1] = Wk_t;  qa.bias[1] = bk;  qa.out[1] = Kb;
    qa.A[2] = xkv_b; qa.W[2] = Wv_t;  qa.bias[2] = bv;  qa.out[2] = Vb;
    qa.A[3] = xq_b;  qa.W[3] = Ws1_t; qa.bias[3] = bs1; qa.out[3] = hb;
    gemm_qkvh<<<dim3(D_MODEL/128, M_ROWS/128, 4), blk, 0, stream>>>(qa);

    // big synth GEMM: 256x256 deep-pipelined kernel, grid (N/256, M/256) = (64, 8)
    gemm256_bf16<<<dim3(NKL/256, M_ROWS/256), dim3(512), 0, stream>>>(hb, Ws2_t, bs2, Sb, NKL);

    attn_mfma<<<dim3(TQ/64, N_HEADS, B_SZ), blk, 0, stream>>>(Qb, Kb, Vb, Sb, kpm, gate, ctxb);

    gemm_bf16<<<dim3(D_MODEL/128, M_ROWS/128), blk, 0, stream>>>(ctxb, Wo_t, bo, d_out, D_MODEL, D_MODEL, 0, 0);
}